// Round 2
// baseline (1616.081 us; speedup 1.0000x reference)
//
#include <hip/hip_runtime.h>

typedef _Float16 half8 __attribute__((ext_vector_type(8)));
typedef _Float16 half4 __attribute__((ext_vector_type(4)));
typedef float f32x4 __attribute__((ext_vector_type(4)));

// Problem constants
#define N_TOK 65536
#define DIM   256
#define KCODE 1024
#define MU_C  0.01f
#define EPS_C 1e-5f

// d_out offsets (floats), reference return order
#define O_Q    0
#define O_LOSS 16777216
#define O_IDX  16777217
#define O_PERP 16842753
#define O_NC   16842754
#define O_NEW  16843778
#define O_EMB  17105922

// d_ws offsets (4-byte words)
#define W_IDX   0         // int[65536]
#define W_CNT   65536     // u32[1024]
#define W_CUR   66560     // u32[1024]
#define W_OFF   67584     // u32[1024]
#define W_CNTF  68608     // float[1024]
#define W_NFLAG 69632     // u32[1]
#define W_ELAT  69633     // float[1]
#define W_FLAG  69696     // int[65536]
#define W_ORDER 135232    // int[65536]
#define W_DW    200768    // float[262144]
#define W_WSQ   462912    // float[1024]
#define W_WH    463936    // _Float16[262144] = 131072 words
// total: 595008 words = 2.38 MB

__device__ __forceinline__ int imin(int a, int b) { return a < b ? a : b; }
__device__ __forceinline__ int imax(int a, int b) { return a > b ? a : b; }

// ---------------------------------------------------------------- zero scratch
__global__ void zero_ws(unsigned* __restrict__ ws) {
    int gid = blockIdx.x * 1024 + threadIdx.x;
    if (gid < 4160) ws[W_CNT + gid] = 0u;   // cnt, cursor, offs, cntf, nflag, elat
}

// ---------------------------------------- W -> f16 convert + row sum-of-squares
__global__ void convert_wsq(const float* __restrict__ W, _Float16* __restrict__ Wh,
                            float* __restrict__ wsq) {
    int gid = blockIdx.x * 256 + threadIdx.x;   // 1024 rows * 64 lanes
    int row = gid >> 6, lane = gid & 63;
    float4 v = *(const float4*)(W + (size_t)row * 256 + lane * 4);
    half4 h;
    h[0] = (_Float16)v.x; h[1] = (_Float16)v.y; h[2] = (_Float16)v.z; h[3] = (_Float16)v.w;
    *(half4*)(Wh + (size_t)row * 256 + lane * 4) = h;
    float s = v.x * v.x + v.y * v.y + v.z * v.z + v.w * v.w;
#pragma unroll
    for (int off = 1; off < 64; off <<= 1) s += __shfl_xor(s, off);
    if (lane == 0) wsq[row] = s;
}

// ------------------------------------------------------------- argmin via MFMA
// Block = 128 tokens; 4 waves, each owns 32 token rows. A (f16 frags, whole
// K=256) lives in registers; B tile [128 codes][64 k] staged to LDS via
// global_load_lds with slot^(row&7) XOR swizzle (pre-swizzled source).
// Scores s = 0.5*wsq - dot + 512 (provably > 0), truncated to 22 bits with the
// code index packed in the low 10 bits -> branchless int-min top-2 tracking.
// Tokens with (top2-top1) < 0.25 are flagged for exact fp32 re-scoring.
__global__ __launch_bounds__(256, 2) void argmin_mfma(
    const float* __restrict__ X, const _Float16* __restrict__ Wh,
    const float* __restrict__ wsq, int* __restrict__ idx_out,
    unsigned* __restrict__ nflag, int* __restrict__ flaglist)
{
    __shared__ _Float16 Bs[128 * 64];   // 16 KB, swizzled row-major [row][k]

    const int tid  = threadIdx.x;
    const int lane = tid & 63;
    const int w    = tid >> 6;          // wave 0..3 -> token rows w*32..w*32+31
    const int l15  = lane & 15;
    const int lk   = lane >> 4;         // 0..3
    const int t0   = blockIdx.x * 128;

    // ---- load A fragments: rows t0 + w*32 + mf*16 + l15, k = g*32 + lk*8 + e
    half8 a[2][8];
#pragma unroll
    for (int mf = 0; mf < 2; ++mf) {
        const float* xr = X + (size_t)(t0 + w * 32 + mf * 16 + l15) * 256 + lk * 8;
#pragma unroll
        for (int g = 0; g < 8; ++g) {
            float4 u0 = *(const float4*)(xr + g * 32);
            float4 u1 = *(const float4*)(xr + g * 32 + 4);
            half8 h;
            h[0] = (_Float16)u0.x; h[1] = (_Float16)u0.y;
            h[2] = (_Float16)u0.z; h[3] = (_Float16)u0.w;
            h[4] = (_Float16)u1.x; h[5] = (_Float16)u1.y;
            h[6] = (_Float16)u1.z; h[7] = (_Float16)u1.w;
            a[mf][g] = h;
        }
    }

    int u1a[8], u2a[8];
#pragma unroll
    for (int i = 0; i < 8; ++i) { u1a[i] = 0x7FFFFFFF; u2a[i] = 0x7FFFFFFF; }

    for (int c = 0; c < 8; ++c) {           // code chunks of 128
        f32x4 acc[2][8];
#pragma unroll
        for (int mf = 0; mf < 2; ++mf)
#pragma unroll
            for (int nf = 0; nf < 8; ++nf) acc[mf][nf] = (f32x4)0.0f;

        for (int ks = 0; ks < 4; ++ks) {    // K steps of 64
            __syncthreads();                // previous B reads done
#pragma unroll
            for (int i = 0; i < 4; ++i) {   // stage 16KB: 4 issues/wave
                int loff = (w * 4 + i) * 1024;          // wave-uniform LDS byte base
                int off  = loff + lane * 16;
                int row  = off >> 7;
                int slot = (off >> 4) & 7;
                const _Float16* src = Wh + (size_t)(c * 128 + row) * 256 + ks * 64
                                         + ((slot ^ (row & 7)) << 3);
                __builtin_amdgcn_global_load_lds(
                    (const __attribute__((address_space(1))) void*)src,
                    (__attribute__((address_space(3))) void*)((char*)Bs + loff),
                    16, 0, 0);
            }
            __syncthreads();                // staging visible (vmcnt(0)+barrier)
#pragma unroll
            for (int kk = 0; kk < 2; ++kk) {
                half8 b[8];
#pragma unroll
                for (int nf = 0; nf < 8; ++nf) {
                    int row  = nf * 16 + l15;
                    int slot = kk * 4 + lk;
                    b[nf] = *(const half8*)((const char*)Bs + row * 128
                                            + ((slot ^ (row & 7)) << 4));
                }
#pragma unroll
                for (int nf = 0; nf < 8; ++nf) {
                    acc[0][nf] = __builtin_amdgcn_mfma_f32_16x16x32_f16(
                        a[0][ks * 2 + kk], b[nf], acc[0][nf], 0, 0, 0);
                    acc[1][nf] = __builtin_amdgcn_mfma_f32_16x16x32_f16(
                        a[1][ks * 2 + kk], b[nf], acc[1][nf], 0, 0, 0);
                }
            }
        }
        // ---- chunk epilogue: scores + packed top-2 update
#pragma unroll
        for (int nf = 0; nf < 8; ++nf) {
            int   code = c * 128 + nf * 16 + l15;
            float wq   = wsq[code];
            float tc   = fmaf(0.5f, wq, 512.0f);
#pragma unroll
            for (int mf = 0; mf < 2; ++mf)
#pragma unroll
                for (int r = 0; r < 4; ++r) {
                    float sv = tc - acc[mf][nf][r];
                    int u = (__float_as_int(sv) & 0xFFFFFC00) | code;
                    int s8 = mf * 4 + r;
                    u2a[s8] = imin(u2a[s8], imax(u1a[s8], u));
                    u1a[s8] = imin(u1a[s8], u);
                }
        }
    }
    // ---- reduce top-2 across the 16 lanes sharing each token row
#pragma unroll
    for (int s8 = 0; s8 < 8; ++s8) {
#pragma unroll
        for (int off = 1; off < 16; off <<= 1) {
            int b1 = __shfl_xor(u1a[s8], off);
            int b2 = __shfl_xor(u2a[s8], off);
            int n2 = imin(imin(u2a[s8], b2), imax(u1a[s8], b1));
            u1a[s8] = imin(u1a[s8], b1);
            u2a[s8] = n2;
        }
    }
    if (l15 == 0) {
#pragma unroll
        for (int s8 = 0; s8 < 8; ++s8) {
            int mf = s8 >> 2, r = s8 & 3;
            int row = t0 + w * 32 + mf * 16 + lk * 4 + r;
            idx_out[row] = u1a[s8] & 1023;
            float s1 = __int_as_float(u1a[s8] & 0xFFFFFC00);
            float s2 = __int_as_float(u2a[s8] & 0xFFFFFC00);
            if (s2 - s1 < 0.25f) {          // near-tie: exact rescore later
                unsigned p = atomicAdd(nflag, 1u);
                flaglist[p] = row;
            }
        }
    }
}

// --------------------------------- exact fp32 re-scoring of flagged tokens
__global__ __launch_bounds__(256) void cleanup_kernel(
    const float* __restrict__ X, const float* __restrict__ W,
    const float* __restrict__ wsq, const unsigned* __restrict__ nflagp,
    const int* __restrict__ flaglist, int* __restrict__ idx_out)
{
    __shared__ float xs[16][256];
    __shared__ float xq[16];
    __shared__ unsigned long long ub[16];
    int n = (int)nflagp[0];
    int tid = threadIdx.x;
    for (int base = blockIdx.x * 16; base < n; base += gridDim.x * 16) {
        int nt = imin(16, n - base);
        for (int j = tid; j < 16 * 64; j += 256) {
            int t = j >> 6, piece = j & 63;
            int tok = flaglist[base + imin(t, nt - 1)];
            ((float4*)xs[t])[piece] = ((const float4*)(X + (size_t)tok * 256))[piece];
        }
        if (tid < 16) ub[tid] = 0x7FFFFFFFFFFFFFFFULL;
        __syncthreads();
        if (tid < 16) {
            float s = 0.f;
            for (int k = 0; k < 256; ++k) s = fmaf(xs[tid][k], xs[tid][k], s);
            xq[tid] = s;
        }
        __syncthreads();
#pragma unroll 1
        for (int pass = 0; pass < 4; ++pass) {
            int c = pass * 256 + tid;
            const float* wr = W + (size_t)c * 256;
            float acc[16];
#pragma unroll
            for (int t = 0; t < 16; ++t) acc[t] = 0.f;
            for (int k = 0; k < 256; k += 4) {
                float4 w4 = *(const float4*)(wr + k);
#pragma unroll
                for (int t = 0; t < 16; ++t) {
                    acc[t] = fmaf(w4.x, xs[t][k],     acc[t]);
                    acc[t] = fmaf(w4.y, xs[t][k + 1], acc[t]);
                    acc[t] = fmaf(w4.z, xs[t][k + 2], acc[t]);
                    acc[t] = fmaf(w4.w, xs[t][k + 3], acc[t]);
                }
            }
            float wq = wsq[c];
#pragma unroll
            for (int t = 0; t < 16; ++t) {
                float s = (xq[t] + wq) - 2.0f * acc[t];   // numpy rounding shape
                unsigned long long pu =
                    ((unsigned long long)(unsigned)__float_as_int(s) << 32) | (unsigned)c;
                atomicMin(&ub[t], pu);
            }
        }
        __syncthreads();
        if (tid < nt) idx_out[flaglist[base + tid]] = (int)(ub[tid] & 0xFFFFFFFFu);
        __syncthreads();
    }
}

// ------------------------------------------- histogram / scan / scatter / dw
__global__ void k_hist(const int* __restrict__ idx, unsigned* __restrict__ cnt) {
    int t = blockIdx.x * 256 + threadIdx.x;
    atomicAdd(&cnt[idx[t]], 1u);
}

__global__ __launch_bounds__(1024) void k_scan(const unsigned* __restrict__ cnt,
                                               unsigned* __restrict__ offs,
                                               float* __restrict__ cntf) {
    __shared__ unsigned s[1024];
    int k = threadIdx.x;
    unsigned v = cnt[k];
    s[k] = v; cntf[k] = (float)v;
    __syncthreads();
    for (int d = 1; d < 1024; d <<= 1) {
        unsigned add = (k >= d) ? s[k - d] : 0u;
        __syncthreads();
        s[k] += add;
        __syncthreads();
    }
    offs[k] = s[k] - v;
}

__global__ void k_scatter(const int* __restrict__ idx, const unsigned* __restrict__ offs,
                          unsigned* __restrict__ cursor, int* __restrict__ order) {
    int t = blockIdx.x * 256 + threadIdx.x;
    int c = idx[t];
    unsigned p = atomicAdd(&cursor[c], 1u);
    order[offs[c] + p] = t;
}

__global__ __launch_bounds__(256) void k_dw(const float* __restrict__ X,
                                            const int* __restrict__ order,
                                            const unsigned* __restrict__ offs,
                                            const unsigned* __restrict__ cnt,
                                            float* __restrict__ dw) {
    int c = blockIdx.x, d = threadIdx.x;
    unsigned base = offs[c], n = cnt[c];
    float acc = 0.f;
    for (unsigned i = 0; i < n; ++i) {
        int t = order[base + i];
        acc += X[(size_t)t * 256 + d];
    }
    dw[(size_t)c * 256 + d] = acc;
}

// --------------------------------------------- streaming epilogue per token
__global__ __launch_bounds__(256) void epilogue_token(
    const float* __restrict__ X, const float* __restrict__ W,
    const int* __restrict__ idx, float* __restrict__ out, float* __restrict__ elat)
{
    int gid = blockIdx.x * 256 + threadIdx.x;
    int t = gid >> 6, q = gid & 63;
    int code = idx[t];
    float4 x4 = ((const float4*)X)[gid];
    float4 w4 = ((const float4*)W)[(size_t)code * 64 + q];
    ((float4*)(out + O_Q))[gid] = w4;
    float dx0 = w4.x - x4.x, dx1 = w4.y - x4.y, dx2 = w4.z - x4.z, dx3 = w4.w - x4.w;
    float e = dx0 * dx0 + dx1 * dx1 + dx2 * dx2 + dx3 * dx3;
    if (q == 0) out[O_IDX + t] = (float)code;
#pragma unroll
    for (int off = 1; off < 64; off <<= 1) e += __shfl_xor(e, off);
    __shared__ float se[4];
    int lane = threadIdx.x & 63, wid = threadIdx.x >> 6;
    if (lane == 0) se[wid] = e;
    __syncthreads();
    if (threadIdx.x == 0) atomicAdd(elat, se[0] + se[1] + se[2] + se[3]);
}

// ------------------------------------------------ cluster EMA + loss + perplexity
__global__ __launch_bounds__(1024) void finalize_small(
    const float* __restrict__ ecs, const float* __restrict__ counts,
    const float* __restrict__ elat, float* __restrict__ out)
{
    int k = threadIdx.x;
    float cnt = counts[k];
    float nc = ecs[k] * (1.0f - MU_C) + MU_C * cnt;
    float p = cnt * (1.0f / 65536.0f);
    float h = p * logf(p + 1e-10f);
    float rn = nc, rh = h;
#pragma unroll
    for (int off = 1; off < 64; off <<= 1) {
        rn += __shfl_xor(rn, off);
        rh += __shfl_xor(rh, off);
    }
    __shared__ float sn[16], sh[16];
    int wid = k >> 6, lane = k & 63;
    if (lane == 0) { sn[wid] = rn; sh[wid] = rh; }
    __syncthreads();
    float n = 0.0f, H = 0.0f;
#pragma unroll
    for (int i = 0; i < 16; ++i) { n += sn[i]; H += sh[i]; }
    out[O_NC + k] = (nc + EPS_C) / (n + 1024.0f * EPS_C) * n;
    if (k == 0) {
        out[O_LOSS] = 0.25f * (elat[0] * (1.0f / 16777216.0f));
        out[O_PERP] = expf(-H);
    }
}

// ------------------------------------------------ new_ema_w / new_embedding
__global__ void finalize_embed(const float* __restrict__ ema_w,
                               const float* __restrict__ dw, float* __restrict__ out)
{
    int gid = blockIdx.x * blockDim.x + threadIdx.x;   // < 262144
    int k = gid >> 8;
    float ew = ema_w[gid] * (1.0f - MU_C) + MU_C * dw[gid];
    out[O_NEW + gid] = ew;
    out[O_EMB + gid] = ew / out[O_NC + k];
}

extern "C" void kernel_launch(void* const* d_in, const int* in_sizes, int n_in,
                              void* d_out, int out_size, void* d_ws, size_t ws_size,
                              hipStream_t stream) {
    const float* X     = (const float*)d_in[0];
    const float* W     = (const float*)d_in[1];
    const float* ema_w = (const float*)d_in[2];
    const float* ecs   = (const float*)d_in[3];
    float*    out    = (float*)d_out;
    unsigned* wsu    = (unsigned*)d_ws;
    float*    wsf    = (float*)d_ws;
    int*      idx    = (int*)d_ws + W_IDX;
    unsigned* cnt    = wsu + W_CNT;
    unsigned* cursor = wsu + W_CUR;
    unsigned* offs   = wsu + W_OFF;
    float*    cntf   = wsf + W_CNTF;
    unsigned* nflag  = wsu + W_NFLAG;
    float*    elat   = wsf + W_ELAT;
    int*      flags  = (int*)d_ws + W_FLAG;
    int*      order  = (int*)d_ws + W_ORDER;
    float*    dw     = wsf + W_DW;
    float*    wsq    = wsf + W_WSQ;
    _Float16* Wh     = (_Float16*)(wsu + W_WH);

    hipLaunchKernelGGL(zero_ws,        dim3(5),     dim3(1024), 0, stream, wsu);
    hipLaunchKernelGGL(convert_wsq,    dim3(256),   dim3(256),  0, stream, W, Wh, wsq);
    hipLaunchKernelGGL(argmin_mfma,    dim3(512),   dim3(256),  0, stream, X, Wh, wsq, idx, nflag, flags);
    hipLaunchKernelGGL(cleanup_kernel, dim3(128),   dim3(256),  0, stream, X, W, wsq, nflag, flags, idx);
    hipLaunchKernelGGL(k_hist,         dim3(256),   dim3(256),  0, stream, idx, cnt);
    hipLaunchKernelGGL(k_scan,         dim3(1),     dim3(1024), 0, stream, cnt, offs, cntf);
    hipLaunchKernelGGL(k_scatter,      dim3(256),   dim3(256),  0, stream, idx, offs, cursor, order);
    hipLaunchKernelGGL(k_dw,           dim3(1024),  dim3(256),  0, stream, X, order, offs, cnt, dw);
    hipLaunchKernelGGL(epilogue_token, dim3(16384), dim3(256),  0, stream, X, W, idx, out, elat);
    hipLaunchKernelGGL(finalize_small, dim3(1),     dim3(1024), 0, stream, ecs, cntf, elat, out);
    hipLaunchKernelGGL(finalize_embed, dim3(1024),  dim3(256),  0, stream, ema_w, dw, out);
}

// Round 3
// 715.122 us; speedup vs baseline: 2.2599x; 2.2599x over previous
//
#include <hip/hip_runtime.h>

typedef _Float16 half8 __attribute__((ext_vector_type(8)));
typedef _Float16 half4 __attribute__((ext_vector_type(4)));
typedef float f32x4 __attribute__((ext_vector_type(4)));

// Problem constants
#define N_TOK 65536
#define DIM   256
#define KCODE 1024
#define MU_C  0.01f
#define EPS_C 1e-5f

// d_out offsets (floats), reference return order
#define O_Q    0
#define O_LOSS 16777216
#define O_IDX  16777217
#define O_PERP 16842753
#define O_NC   16842754
#define O_NEW  16843778
#define O_EMB  17105922

// d_ws offsets (4-byte words)
#define W_IDX   0         // int[65536]
#define W_CNT   65536     // u32[1024]
#define W_CUR   66560     // u32[1024]
#define W_OFF   67584     // u32[1024]
#define W_CNTF  68608     // float[1024]
#define W_NFLAG 69632     // u32[1]
#define W_ELAT  69633     // float[1]
#define W_FLAG  69696     // int[65536]
#define W_ORDER 135232    // int[65536]
#define W_DW    200768    // float[262144]
#define W_WSQ   462912    // float[1024]
#define W_WH    463936    // _Float16[262144] = 131072 words

__device__ __forceinline__ int imin(int a, int b) { return a < b ? a : b; }
__device__ __forceinline__ int imax(int a, int b) { return a > b ? a : b; }

// ---------------------------------------- W -> f16 convert + row sum-of-squares
__global__ void convert_wsq(const float* __restrict__ W, _Float16* __restrict__ Wh,
                            float* __restrict__ wsq) {
    int gid = blockIdx.x * 256 + threadIdx.x;   // 1024 rows * 64 lanes
    int row = gid >> 6, lane = gid & 63;
    float4 v = *(const float4*)(W + (size_t)row * 256 + lane * 4);
    half4 h;
    h[0] = (_Float16)v.x; h[1] = (_Float16)v.y; h[2] = (_Float16)v.z; h[3] = (_Float16)v.w;
    *(half4*)(Wh + (size_t)row * 256 + lane * 4) = h;
    float s = v.x * v.x + v.y * v.y + v.z * v.z + v.w * v.w;
#pragma unroll
    for (int off = 1; off < 64; off <<= 1) s += __shfl_xor(s, off);
    if (lane == 0) wsq[row] = s;
}

// ------------------------------------------------------------- argmin via MFMA
// Block = 128 tokens, 4 waves x 32 rows. A (f16, whole K=256) in registers.
// B chunks of 64 codes double-buffered in LDS (2 x 32KB), 2-phase pipeline:
// STAGE(c+1) issued before compute(c), one barrier per chunk.
// XOR swizzle (16B-slot ^ (row&7)) applied on the pre-swizzled global source
// and on the ds_read address (both-sides involution).
__global__ __launch_bounds__(256, 2) void argmin_mfma(
    const float* __restrict__ X, const _Float16* __restrict__ Wh,
    const float* __restrict__ wsq, int* __restrict__ idx_out,
    unsigned* __restrict__ nflag, int* __restrict__ flaglist)
{
    __shared__ _Float16 Bs[2][64 * 256];   // 2 x 32 KB

    const int tid  = threadIdx.x;
    const int lane = tid & 63;
    const int w    = tid >> 6;          // wave 0..3 -> token rows w*32..
    const int l15  = lane & 15;
    const int lk   = lane >> 4;         // 0..3
    const int t0   = blockIdx.x * 128;

    // ---- A fragments: rows t0 + w*32 + mf*16 + l15, k = g*32 + lk*8 + e
    half8 a[2][8];
#pragma unroll
    for (int mf = 0; mf < 2; ++mf) {
        const float* xr = X + (size_t)(t0 + w * 32 + mf * 16 + l15) * 256 + lk * 8;
#pragma unroll
        for (int g = 0; g < 8; ++g) {
            float4 u0 = *(const float4*)(xr + g * 32);
            float4 u1 = *(const float4*)(xr + g * 32 + 4);
            half8 h;
            h[0] = (_Float16)u0.x; h[1] = (_Float16)u0.y;
            h[2] = (_Float16)u0.z; h[3] = (_Float16)u0.w;
            h[4] = (_Float16)u1.x; h[5] = (_Float16)u1.y;
            h[6] = (_Float16)u1.z; h[7] = (_Float16)u1.w;
            a[mf][g] = h;
        }
    }

    int u1a[8], u2a[8];
#pragma unroll
    for (int i = 0; i < 8; ++i) { u1a[i] = 0x7FFFFFFF; u2a[i] = 0x7FFFFFFF; }

#define STAGE(cc, bb)                                                          \
    _Pragma("unroll")                                                          \
    for (int i = 0; i < 8; ++i) {                                              \
        int loff = (w * 8 + i) * 1024;                                         \
        int off  = loff + lane * 16;                                           \
        int row  = off >> 9;                                                   \
        int slot = (off >> 4) & 31;                                            \
        const _Float16* src = Wh + (size_t)((cc) * 64 + row) * 256             \
                                 + ((slot ^ (row & 7)) << 3);                  \
        __builtin_amdgcn_global_load_lds(                                      \
            (const __attribute__((address_space(1))) void*)src,                \
            (__attribute__((address_space(3))) void*)((char*)Bs[bb] + loff),   \
            16, 0, 0);                                                         \
    }

    STAGE(0, 0);
    __syncthreads();                      // vmcnt(0) drain: buf0 ready

    for (int c = 0; c < 16; ++c) {        // 16 chunks of 64 codes
        const int cur = c & 1;
        if (c < 15) { STAGE(c + 1, cur ^ 1); }   // overlap with compute

        f32x4 acc[2][4];
#pragma unroll
        for (int mf = 0; mf < 2; ++mf)
#pragma unroll
            for (int nf = 0; nf < 4; ++nf) acc[mf][nf] = (f32x4)0.0f;

#pragma unroll
        for (int ks = 0; ks < 4; ++ks) {
#pragma unroll
            for (int kk = 0; kk < 2; ++kk) {
                half8 b4[4];
#pragma unroll
                for (int nf = 0; nf < 4; ++nf) {
                    int row  = nf * 16 + l15;
                    int slot = ks * 8 + kk * 4 + lk;
                    b4[nf] = *(const half8*)((const char*)Bs[cur]
                              + row * 512 + ((slot ^ (row & 7)) << 4));
                }
#pragma unroll
                for (int nf = 0; nf < 4; ++nf) {
                    acc[0][nf] = __builtin_amdgcn_mfma_f32_16x16x32_f16(
                        a[0][ks * 2 + kk], b4[nf], acc[0][nf], 0, 0, 0);
                    acc[1][nf] = __builtin_amdgcn_mfma_f32_16x16x32_f16(
                        a[1][ks * 2 + kk], b4[nf], acc[1][nf], 0, 0, 0);
                }
            }
        }
        // ---- chunk epilogue: scores + packed top-2 update
#pragma unroll
        for (int nf = 0; nf < 4; ++nf) {
            int   code = c * 64 + nf * 16 + l15;
            float tc   = fmaf(0.5f, wsq[code], 512.0f);
#pragma unroll
            for (int mf = 0; mf < 2; ++mf)
#pragma unroll
                for (int r = 0; r < 4; ++r) {
                    float sv = tc - acc[mf][nf][r];
                    int u = (__float_as_int(sv) & 0xFFFFFC00) | code;
                    int s8 = mf * 4 + r;
                    u2a[s8] = imin(u2a[s8], imax(u1a[s8], u));
                    u1a[s8] = imin(u1a[s8], u);
                }
        }
        __syncthreads();                  // staging(c+1) done; reads(c) done
    }
#undef STAGE

    // ---- reduce top-2 across the 16 lanes sharing each token row
#pragma unroll
    for (int s8 = 0; s8 < 8; ++s8) {
#pragma unroll
        for (int off = 1; off < 16; off <<= 1) {
            int b1 = __shfl_xor(u1a[s8], off);
            int b2 = __shfl_xor(u2a[s8], off);
            int n2 = imin(imin(u2a[s8], b2), imax(u1a[s8], b1));
            u1a[s8] = imin(u1a[s8], b1);
            u2a[s8] = n2;
        }
    }
    if (l15 == 0) {
#pragma unroll
        for (int s8 = 0; s8 < 8; ++s8) {
            int mf = s8 >> 2, r = s8 & 3;
            int row = t0 + w * 32 + mf * 16 + lk * 4 + r;
            idx_out[row] = u1a[s8] & 1023;
            float s1 = __int_as_float(u1a[s8] & 0xFFFFFC00);
            float s2 = __int_as_float(u2a[s8] & 0xFFFFFC00);
            if (s2 - s1 < 0.25f) {          // near-tie: exact rescore later
                unsigned p = atomicAdd(nflag, 1u);
                flaglist[p] = row;
            }
        }
    }
}

// --------------------------------- exact fp32 re-scoring of flagged tokens
__global__ __launch_bounds__(256) void cleanup_kernel(
    const float* __restrict__ X, const float* __restrict__ W,
    const float* __restrict__ wsq, const unsigned* __restrict__ nflagp,
    const int* __restrict__ flaglist, int* __restrict__ idx_out)
{
    __shared__ float xs[16][256];
    __shared__ float xq[16];
    __shared__ unsigned long long ub[16];
    int n = (int)nflagp[0];
    int tid = threadIdx.x;
    for (int base = blockIdx.x * 16; base < n; base += gridDim.x * 16) {
        int nt = imin(16, n - base);
        for (int j = tid; j < 16 * 64; j += 256) {
            int t = j >> 6, piece = j & 63;
            int tok = flaglist[base + imin(t, nt - 1)];
            ((float4*)xs[t])[piece] = ((const float4*)(X + (size_t)tok * 256))[piece];
        }
        if (tid < 16) ub[tid] = 0x7FFFFFFFFFFFFFFFULL;
        __syncthreads();
        if (tid < 16) {
            float s = 0.f;
            for (int k = 0; k < 256; ++k) s = fmaf(xs[tid][k], xs[tid][k], s);
            xq[tid] = s;
        }
        __syncthreads();
#pragma unroll 1
        for (int pass = 0; pass < 4; ++pass) {
            int c = pass * 256 + tid;
            const float* wr = W + (size_t)c * 256;
            float acc[16];
#pragma unroll
            for (int t = 0; t < 16; ++t) acc[t] = 0.f;
            for (int k = 0; k < 256; k += 4) {
                float4 w4 = *(const float4*)(wr + k);
#pragma unroll
                for (int t = 0; t < 16; ++t) {
                    acc[t] = fmaf(w4.x, xs[t][k],     acc[t]);
                    acc[t] = fmaf(w4.y, xs[t][k + 1], acc[t]);
                    acc[t] = fmaf(w4.z, xs[t][k + 2], acc[t]);
                    acc[t] = fmaf(w4.w, xs[t][k + 3], acc[t]);
                }
            }
            float wq = wsq[c];
#pragma unroll
            for (int t = 0; t < 16; ++t) {
                float s = (xq[t] + wq) - 2.0f * acc[t];
                unsigned long long pu =
                    ((unsigned long long)(unsigned)__float_as_int(s) << 32) | (unsigned)c;
                atomicMin(&ub[t], pu);
            }
        }
        __syncthreads();
        if (tid < nt) idx_out[flaglist[base + tid]] = (int)(ub[tid] & 0xFFFFFFFFu);
        __syncthreads();
    }
}

// ------------------------------------------- histogram / scan / scatter / dw
__global__ void k_hist(const int* __restrict__ idx, unsigned* __restrict__ cnt) {
    int t = blockIdx.x * 256 + threadIdx.x;
    atomicAdd(&cnt[idx[t]], 1u);
}

__global__ __launch_bounds__(1024) void k_scan(const unsigned* __restrict__ cnt,
                                               unsigned* __restrict__ offs,
                                               float* __restrict__ cntf) {
    __shared__ unsigned s[1024];
    int k = threadIdx.x;
    unsigned v = cnt[k];
    s[k] = v; cntf[k] = (float)v;
    __syncthreads();
    for (int d = 1; d < 1024; d <<= 1) {
        unsigned add = (k >= d) ? s[k - d] : 0u;
        __syncthreads();
        s[k] += add;
        __syncthreads();
    }
    offs[k] = s[k] - v;
}

__global__ void k_scatter(const int* __restrict__ idx, const unsigned* __restrict__ offs,
                          unsigned* __restrict__ cursor, int* __restrict__ order) {
    int t = blockIdx.x * 256 + threadIdx.x;
    int c = idx[t];
    unsigned p = atomicAdd(&cursor[c], 1u);
    order[offs[c] + p] = t;
}

// Skew-immune dw: each wave owns 16 contiguous positions of the sorted order
// array; accumulates runs of equal code in registers; one float4-atomic flush
// per run boundary. Hot codes are split across many waves.
__global__ __launch_bounds__(256) void k_dw(const float* __restrict__ X,
                                            const int* __restrict__ order,
                                            const int* __restrict__ idx,
                                            float* __restrict__ dw)
{
    int gw   = (blockIdx.x * 256 + threadIdx.x) >> 6;   // 4096 waves
    int lane = threadIdx.x & 63;
    int p0 = gw * 16;
    float4 acc = make_float4(0.f, 0.f, 0.f, 0.f);
    int cur = -1;
#pragma unroll 4
    for (int i = 0; i < 16; ++i) {
        int t = order[p0 + i];
        int c = idx[t];
        float4 x4 = *(const float4*)(X + (size_t)t * 256 + lane * 4);
        if (c != cur) {                   // wave-uniform branch
            if (cur >= 0) {
                float* dwp = dw + (size_t)cur * 256 + lane * 4;
                atomicAdd(dwp + 0, acc.x); atomicAdd(dwp + 1, acc.y);
                atomicAdd(dwp + 2, acc.z); atomicAdd(dwp + 3, acc.w);
            }
            cur = c; acc = x4;
        } else {
            acc.x += x4.x; acc.y += x4.y; acc.z += x4.z; acc.w += x4.w;
        }
    }
    if (cur >= 0) {
        float* dwp = dw + (size_t)cur * 256 + lane * 4;
        atomicAdd(dwp + 0, acc.x); atomicAdd(dwp + 1, acc.y);
        atomicAdd(dwp + 2, acc.z); atomicAdd(dwp + 3, acc.w);
    }
}

// --------------------------------------------- streaming epilogue per token
__global__ __launch_bounds__(256) void epilogue_token(
    const float* __restrict__ X, const float* __restrict__ W,
    const int* __restrict__ idx, float* __restrict__ out, float* __restrict__ elat)
{
    int gid = blockIdx.x * 256 + threadIdx.x;
    int t = gid >> 6, q = gid & 63;
    int code = idx[t];
    float4 x4 = ((const float4*)X)[gid];
    float4 w4 = ((const float4*)W)[(size_t)code * 64 + q];
    ((float4*)(out + O_Q))[gid] = w4;
    float dx0 = w4.x - x4.x, dx1 = w4.y - x4.y, dx2 = w4.z - x4.z, dx3 = w4.w - x4.w;
    float e = dx0 * dx0 + dx1 * dx1 + dx2 * dx2 + dx3 * dx3;
    if (q == 0) out[O_IDX + t] = (float)code;
#pragma unroll
    for (int off = 1; off < 64; off <<= 1) e += __shfl_xor(e, off);
    __shared__ float se[4];
    int lane = threadIdx.x & 63, wid = threadIdx.x >> 6;
    if (lane == 0) se[wid] = e;
    __syncthreads();
    if (threadIdx.x == 0) atomicAdd(elat, se[0] + se[1] + se[2] + se[3]);
}

// ------------------------------------------------ cluster EMA + loss + perplexity
__global__ __launch_bounds__(1024) void finalize_small(
    const float* __restrict__ ecs, const float* __restrict__ counts,
    const float* __restrict__ elat, float* __restrict__ out)
{
    int k = threadIdx.x;
    float cnt = counts[k];
    float nc = ecs[k] * (1.0f - MU_C) + MU_C * cnt;
    float p = cnt * (1.0f / 65536.0f);
    float h = p * logf(p + 1e-10f);
    float rn = nc, rh = h;
#pragma unroll
    for (int off = 1; off < 64; off <<= 1) {
        rn += __shfl_xor(rn, off);
        rh += __shfl_xor(rh, off);
    }
    __shared__ float sn[16], sh[16];
    int wid = k >> 6, lane = k & 63;
    if (lane == 0) { sn[wid] = rn; sh[wid] = rh; }
    __syncthreads();
    float n = 0.0f, H = 0.0f;
#pragma unroll
    for (int i = 0; i < 16; ++i) { n += sn[i]; H += sh[i]; }
    out[O_NC + k] = (nc + EPS_C) / (n + 1024.0f * EPS_C) * n;
    if (k == 0) {
        out[O_LOSS] = 0.25f * (elat[0] * (1.0f / 16777216.0f));
        out[O_PERP] = expf(-H);
    }
}

// ------------------------------------------------ new_ema_w / new_embedding
__global__ void finalize_embed(const float* __restrict__ ema_w,
                               const float* __restrict__ dw, float* __restrict__ out)
{
    int gid = blockIdx.x * blockDim.x + threadIdx.x;   // < 262144
    int k = gid >> 8;
    float ew = ema_w[gid] * (1.0f - MU_C) + MU_C * dw[gid];
    out[O_NEW + gid] = ew;
    out[O_EMB + gid] = ew / out[O_NC + k];
}

extern "C" void kernel_launch(void* const* d_in, const int* in_sizes, int n_in,
                              void* d_out, int out_size, void* d_ws, size_t ws_size,
                              hipStream_t stream) {
    const float* X     = (const float*)d_in[0];
    const float* W     = (const float*)d_in[1];
    const float* ema_w = (const float*)d_in[2];
    const float* ecs   = (const float*)d_in[3];
    float*    out    = (float*)d_out;
    unsigned* wsu    = (unsigned*)d_ws;
    float*    wsf    = (float*)d_ws;
    int*      idx    = (int*)d_ws + W_IDX;
    unsigned* cnt    = wsu + W_CNT;
    unsigned* cursor = wsu + W_CUR;
    unsigned* offs   = wsu + W_OFF;
    float*    cntf   = wsf + W_CNTF;
    unsigned* nflag  = wsu + W_NFLAG;
    float*    elat   = wsf + W_ELAT;
    int*      flags  = (int*)d_ws + W_FLAG;
    int*      order  = (int*)d_ws + W_ORDER;
    float*    dw     = wsf + W_DW;
    float*    wsq    = wsf + W_WSQ;
    _Float16* Wh     = (_Float16*)(wsu + W_WH);

    hipMemsetAsync(wsu + W_CNT, 0, 4098 * sizeof(unsigned), stream);  // cnt..elat
    hipMemsetAsync(wsf + W_DW,  0, 262144 * sizeof(float),  stream);  // dw
    hipLaunchKernelGGL(convert_wsq,    dim3(256),   dim3(256),  0, stream, W, Wh, wsq);
    hipLaunchKernelGGL(argmin_mfma,    dim3(512),   dim3(256),  0, stream, X, Wh, wsq, idx, nflag, flags);
    hipLaunchKernelGGL(cleanup_kernel, dim3(256),   dim3(256),  0, stream, X, W, wsq, nflag, flags, idx);
    hipLaunchKernelGGL(k_hist,         dim3(256),   dim3(256),  0, stream, idx, cnt);
    hipLaunchKernelGGL(k_scan,         dim3(1),     dim3(1024), 0, stream, cnt, offs, cntf);
    hipLaunchKernelGGL(k_scatter,      dim3(256),   dim3(256),  0, stream, idx, offs, cursor, order);
    hipLaunchKernelGGL(k_dw,           dim3(1024),  dim3(256),  0, stream, X, order, idx, dw);
    hipLaunchKernelGGL(epilogue_token, dim3(16384), dim3(256),  0, stream, X, W, idx, out, elat);
    hipLaunchKernelGGL(finalize_small, dim3(1),     dim3(1024), 0, stream, ecs, cntf, elat, out);
    hipLaunchKernelGGL(finalize_embed, dim3(1024),  dim3(256),  0, stream, ema_w, dw, out);
}

// Round 4
// 507.871 us; speedup vs baseline: 3.1821x; 1.4081x over previous
//
#include <hip/hip_runtime.h>

typedef _Float16 half8 __attribute__((ext_vector_type(8)));
typedef _Float16 half4 __attribute__((ext_vector_type(4)));
typedef float f32x4 __attribute__((ext_vector_type(4)));

// Problem constants
#define N_TOK 65536
#define DIM   256
#define KCODE 1024
#define MU_C  0.01f
#define EPS_C 1e-5f

// d_out offsets (floats), reference return order
#define O_Q    0
#define O_LOSS 16777216
#define O_IDX  16777217
#define O_PERP 16842753
#define O_NC   16842754
#define O_NEW  16843778
#define O_EMB  17105922

// d_ws offsets (4-byte words)
#define W_IDX   0         // int[65536]
#define W_CNT   65536     // u32[1024]
#define W_CUR   66560     // u32[1024]
#define W_OFF   67584     // u32[1024]
#define W_CNTF  68608     // float[1024]
#define W_NFLAG 69632     // u32[1]
#define W_ELAT  69633     // float[1]  (unused now)
#define W_FLAG  69696     // int[65536]
#define W_ORDER 135232    // int[65536]
#define W_DW    200768    // float[262144]
#define W_WSQ   462912    // float[1024]
#define W_WH    463936    // _Float16[262144] = 131072 words
#define W_XSQF  595008    // float[65536]  xsq of flagged tokens (compacted)
#define W_ELATA 660544    // float[16384]  per-block e_latent partial sums
// total: 676928 words = 2.71 MB

__device__ __forceinline__ int imin(int a, int b) { return a < b ? a : b; }
__device__ __forceinline__ int imax(int a, int b) { return a > b ? a : b; }

// ---------------------------------------- W -> f16 convert + row sum-of-squares
__global__ void convert_wsq(const float* __restrict__ W, _Float16* __restrict__ Wh,
                            float* __restrict__ wsq) {
    int gid = blockIdx.x * 256 + threadIdx.x;   // 1024 rows * 64 lanes
    int row = gid >> 6, lane = gid & 63;
    float4 v = *(const float4*)(W + (size_t)row * 256 + lane * 4);
    half4 h;
    h[0] = (_Float16)v.x; h[1] = (_Float16)v.y; h[2] = (_Float16)v.z; h[3] = (_Float16)v.w;
    *(half4*)(Wh + (size_t)row * 256 + lane * 4) = h;
    float s = v.x * v.x + v.y * v.y + v.z * v.z + v.w * v.w;
#pragma unroll
    for (int off = 1; off < 64; off <<= 1) s += __shfl_xor(s, off);
    if (lane == 0) wsq[row] = s;
}

// ------------------------------------------------------------- argmin via MFMA
// Block = 128 tokens, 4 waves x 32 rows. A (f16, whole K=256) in registers.
// B chunks of 64 codes double-buffered in LDS (2 x 32KB), 2-phase pipeline.
// Packed top-2 tracking; tokens with truncated gap < 0.125 flagged for exact
// fp32 re-scoring (trunc quantum 0.0625 -> f16 gap >= 0.0625 = 6.9 sigma).
__global__ __launch_bounds__(256, 2) void argmin_mfma(
    const float* __restrict__ X, const _Float16* __restrict__ Wh,
    const float* __restrict__ wsq, int* __restrict__ idx_out,
    unsigned* __restrict__ nflag, int* __restrict__ flaglist)
{
    __shared__ _Float16 Bs[2][64 * 256];   // 2 x 32 KB

    const int tid  = threadIdx.x;
    const int lane = tid & 63;
    const int w    = tid >> 6;
    const int l15  = lane & 15;
    const int lk   = lane >> 4;
    const int t0   = blockIdx.x * 128;

    half8 a[2][8];
#pragma unroll
    for (int mf = 0; mf < 2; ++mf) {
        const float* xr = X + (size_t)(t0 + w * 32 + mf * 16 + l15) * 256 + lk * 8;
#pragma unroll
        for (int g = 0; g < 8; ++g) {
            float4 u0 = *(const float4*)(xr + g * 32);
            float4 u1 = *(const float4*)(xr + g * 32 + 4);
            half8 h;
            h[0] = (_Float16)u0.x; h[1] = (_Float16)u0.y;
            h[2] = (_Float16)u0.z; h[3] = (_Float16)u0.w;
            h[4] = (_Float16)u1.x; h[5] = (_Float16)u1.y;
            h[6] = (_Float16)u1.z; h[7] = (_Float16)u1.w;
            a[mf][g] = h;
        }
    }

    int u1a[8], u2a[8];
#pragma unroll
    for (int i = 0; i < 8; ++i) { u1a[i] = 0x7FFFFFFF; u2a[i] = 0x7FFFFFFF; }

#define STAGE(cc, bb)                                                          \
    _Pragma("unroll")                                                          \
    for (int i = 0; i < 8; ++i) {                                              \
        int loff = (w * 8 + i) * 1024;                                         \
        int off  = loff + lane * 16;                                           \
        int row  = off >> 9;                                                   \
        int slot = (off >> 4) & 31;                                            \
        const _Float16* src = Wh + (size_t)((cc) * 64 + row) * 256             \
                                 + ((slot ^ (row & 7)) << 3);                  \
        __builtin_amdgcn_global_load_lds(                                      \
            (const __attribute__((address_space(1))) void*)src,                \
            (__attribute__((address_space(3))) void*)((char*)Bs[bb] + loff),   \
            16, 0, 0);                                                         \
    }

    STAGE(0, 0);
    __syncthreads();

    for (int c = 0; c < 16; ++c) {
        const int cur = c & 1;
        if (c < 15) { STAGE(c + 1, cur ^ 1); }

        f32x4 acc[2][4];
#pragma unroll
        for (int mf = 0; mf < 2; ++mf)
#pragma unroll
            for (int nf = 0; nf < 4; ++nf) acc[mf][nf] = (f32x4)0.0f;

#pragma unroll
        for (int ks = 0; ks < 4; ++ks) {
#pragma unroll
            for (int kk = 0; kk < 2; ++kk) {
                half8 b4[4];
#pragma unroll
                for (int nf = 0; nf < 4; ++nf) {
                    int row  = nf * 16 + l15;
                    int slot = ks * 8 + kk * 4 + lk;
                    b4[nf] = *(const half8*)((const char*)Bs[cur]
                              + row * 512 + ((slot ^ (row & 7)) << 4));
                }
#pragma unroll
                for (int nf = 0; nf < 4; ++nf) {
                    acc[0][nf] = __builtin_amdgcn_mfma_f32_16x16x32_f16(
                        a[0][ks * 2 + kk], b4[nf], acc[0][nf], 0, 0, 0);
                    acc[1][nf] = __builtin_amdgcn_mfma_f32_16x16x32_f16(
                        a[1][ks * 2 + kk], b4[nf], acc[1][nf], 0, 0, 0);
                }
            }
        }
#pragma unroll
        for (int nf = 0; nf < 4; ++nf) {
            int   code = c * 64 + nf * 16 + l15;
            float tc   = fmaf(0.5f, wsq[code], 512.0f);
#pragma unroll
            for (int mf = 0; mf < 2; ++mf)
#pragma unroll
                for (int r = 0; r < 4; ++r) {
                    float sv = tc - acc[mf][nf][r];
                    int u = (__float_as_int(sv) & 0xFFFFFC00) | code;
                    int s8 = mf * 4 + r;
                    u2a[s8] = imin(u2a[s8], imax(u1a[s8], u));
                    u1a[s8] = imin(u1a[s8], u);
                }
        }
        __syncthreads();
    }
#undef STAGE

#pragma unroll
    for (int s8 = 0; s8 < 8; ++s8) {
#pragma unroll
        for (int off = 1; off < 16; off <<= 1) {
            int b1 = __shfl_xor(u1a[s8], off);
            int b2 = __shfl_xor(u2a[s8], off);
            int n2 = imin(imin(u2a[s8], b2), imax(u1a[s8], b1));
            u1a[s8] = imin(u1a[s8], b1);
            u2a[s8] = n2;
        }
    }
    if (l15 == 0) {
#pragma unroll
        for (int s8 = 0; s8 < 8; ++s8) {
            int mf = s8 >> 2, r = s8 & 3;
            int row = t0 + w * 32 + mf * 16 + lk * 4 + r;
            idx_out[row] = u1a[s8] & 1023;
            float s1 = __int_as_float(u1a[s8] & 0xFFFFFC00);
            float s2 = __int_as_float(u2a[s8] & 0xFFFFFC00);
            if (s2 - s1 < 0.125f) {
                unsigned p = atomicAdd(nflag, 1u);
                flaglist[p] = row;
            }
        }
    }
}

// ------------------------------------ xsq for flagged tokens (compacted array)
__global__ void cleanup_xsq(const float* __restrict__ X,
                            const unsigned* __restrict__ nflagp,
                            const int* __restrict__ flaglist,
                            float* __restrict__ xsqf) {
    int n = (int)nflagp[0];
    int wid  = (blockIdx.x * 256 + threadIdx.x) >> 6;   // 1024 waves
    int lane = threadIdx.x & 63;
    for (int i = wid; i < n; i += 1024) {
        const float* row = X + (size_t)flaglist[i] * 256;
        float4 v = *(const float4*)(row + lane * 4);
        float s = v.x * v.x + v.y * v.y + v.z * v.z + v.w * v.w;
#pragma unroll
        for (int off = 1; off < 64; off <<= 1) s += __shfl_xor(s, off);
        if (lane == 0) xsqf[i] = s;
    }
}

// ------------------- exact fp32 re-scoring: GEMM tile over gathered flagged rows
// 128 tokens x 1024 codes, BK=16, 256 threads, 8x8 microtile (R1-proven).
#define BM 128
#define BN 128
#define BK 16

__global__ __launch_bounds__(256) void cleanup_gemm(
    const float* __restrict__ X, const float* __restrict__ W,
    const float* __restrict__ wsq, const unsigned* __restrict__ nflagp,
    const int* __restrict__ flaglist, const float* __restrict__ xsqf,
    int* __restrict__ idx_out)
{
    __shared__ float xs [BK][BM];
    __shared__ float wps[BK][BN];
    __shared__ float wsq_s[BN];

    const int n = (int)nflagp[0];
    const int tid  = threadIdx.x;
    const int tx   = tid & 15;
    const int ty   = tid >> 4;
    const int trow = tid >> 1;
    const int khalf = (tid & 1) * 8;

    for (int tile = blockIdx.x; tile * BM < n; tile += gridDim.x) {
        const int t0 = tile * BM;
        const int gtok = flaglist[imin(t0 + trow, n - 1)];   // gathered row id

        float xsq_r[8];
#pragma unroll
        for (int i = 0; i < 8; ++i) xsq_r[i] = xsqf[imin(t0 + ty * 8 + i, n - 1)];

        float minv[8]; int mini[8];
#pragma unroll
        for (int i = 0; i < 8; ++i) { minv[i] = 3.402823466e+38f; mini[i] = 0; }

        for (int cc = 0; cc < KCODE / BN; ++cc) {
            const int c0 = cc * BN;
            float acc[8][8];
#pragma unroll
            for (int i = 0; i < 8; ++i)
#pragma unroll
                for (int j = 0; j < 8; ++j) acc[i][j] = 0.0f;

            for (int ks = 0; ks < DIM / BK; ++ks) {
                const int kb = ks * BK;
                __syncthreads();
                {
                    const float* xr = X + (size_t)gtok * DIM + kb + khalf;
                    float4 v0 = *(const float4*)xr;
                    float4 v1 = *(const float4*)(xr + 4);
                    xs[khalf + 0][trow] = v0.x; xs[khalf + 1][trow] = v0.y;
                    xs[khalf + 2][trow] = v0.z; xs[khalf + 3][trow] = v0.w;
                    xs[khalf + 4][trow] = v1.x; xs[khalf + 5][trow] = v1.y;
                    xs[khalf + 6][trow] = v1.z; xs[khalf + 7][trow] = v1.w;
                    const float* wr = W + (size_t)(c0 + trow) * DIM + kb + khalf;
                    float4 u0 = *(const float4*)wr;
                    float4 u1 = *(const float4*)(wr + 4);
                    wps[khalf + 0][trow] = u0.x; wps[khalf + 1][trow] = u0.y;
                    wps[khalf + 2][trow] = u0.z; wps[khalf + 3][trow] = u0.w;
                    wps[khalf + 4][trow] = u1.x; wps[khalf + 5][trow] = u1.y;
                    wps[khalf + 6][trow] = u1.z; wps[khalf + 7][trow] = u1.w;
                    if (ks == 0 && tid < BN) wsq_s[tid] = wsq[c0 + tid];
                }
                __syncthreads();
#pragma unroll
                for (int kl = 0; kl < BK; ++kl) {
                    float4 a0 = *(const float4*)&xs [kl][ty * 8];
                    float4 a1 = *(const float4*)&xs [kl][ty * 8 + 4];
                    float4 b0 = *(const float4*)&wps[kl][tx * 8];
                    float4 b1 = *(const float4*)&wps[kl][tx * 8 + 4];
                    float a[8] = {a0.x, a0.y, a0.z, a0.w, a1.x, a1.y, a1.z, a1.w};
                    float b[8] = {b0.x, b0.y, b0.z, b0.w, b1.x, b1.y, b1.z, b1.w};
#pragma unroll
                    for (int i = 0; i < 8; ++i)
#pragma unroll
                        for (int j = 0; j < 8; ++j)
                            acc[i][j] = fmaf(a[i], b[j], acc[i][j]);
                }
            }
            // exact-rounding scores, strict < keeps lowest index
#pragma unroll
            for (int i = 0; i < 8; ++i) {
#pragma unroll
                for (int j = 0; j < 8; ++j) {
                    float t1 = xsq_r[i] + wsq_s[tx * 8 + j];
                    float s  = t1 - 2.0f * acc[i][j];
                    int   c  = c0 + tx * 8 + j;
                    if (s < minv[i]) { minv[i] = s; mini[i] = c; }
                }
            }
        }
#pragma unroll
        for (int i = 0; i < 8; ++i) {
#pragma unroll
            for (int off = 1; off < 16; off <<= 1) {
                float ov = __shfl_xor(minv[i], off);
                int   oi = __shfl_xor(mini[i], off);
                if (ov < minv[i] || (ov == minv[i] && oi < mini[i])) {
                    minv[i] = ov; mini[i] = oi;
                }
            }
        }
        if (tx == 0) {
#pragma unroll
            for (int i = 0; i < 8; ++i) {
                int pos = t0 + ty * 8 + i;
                if (pos < n) idx_out[flaglist[pos]] = mini[i];
            }
        }
        __syncthreads();
    }
}

// ------------------------------------------- histogram / scan / scatter / dw
__global__ void k_hist(const int* __restrict__ idx, unsigned* __restrict__ cnt) {
    int t = blockIdx.x * 256 + threadIdx.x;
    atomicAdd(&cnt[idx[t]], 1u);
}

__global__ __launch_bounds__(1024) void k_scan(const unsigned* __restrict__ cnt,
                                               unsigned* __restrict__ offs,
                                               float* __restrict__ cntf) {
    __shared__ unsigned s[1024];
    int k = threadIdx.x;
    unsigned v = cnt[k];
    s[k] = v; cntf[k] = (float)v;
    __syncthreads();
    for (int d = 1; d < 1024; d <<= 1) {
        unsigned add = (k >= d) ? s[k - d] : 0u;
        __syncthreads();
        s[k] += add;
        __syncthreads();
    }
    offs[k] = s[k] - v;
}

__global__ void k_scatter(const int* __restrict__ idx, const unsigned* __restrict__ offs,
                          unsigned* __restrict__ cursor, int* __restrict__ order) {
    int t = blockIdx.x * 256 + threadIdx.x;
    int c = idx[t];
    unsigned p = atomicAdd(&cursor[c], 1u);
    order[offs[c] + p] = t;
}

// Skew-immune dw: each wave owns 16 contiguous sorted positions, register-
// accumulates runs, one float4-atomic flush per run boundary.
__global__ __launch_bounds__(256) void k_dw(const float* __restrict__ X,
                                            const int* __restrict__ order,
                                            const int* __restrict__ idx,
                                            float* __restrict__ dw)
{
    int gw   = (blockIdx.x * 256 + threadIdx.x) >> 6;   // 4096 waves
    int lane = threadIdx.x & 63;
    int p0 = gw * 16;
    float4 acc = make_float4(0.f, 0.f, 0.f, 0.f);
    int cur = -1;
#pragma unroll 4
    for (int i = 0; i < 16; ++i) {
        int t = order[p0 + i];
        int c = idx[t];
        float4 x4 = *(const float4*)(X + (size_t)t * 256 + lane * 4);
        if (c != cur) {
            if (cur >= 0) {
                float* dwp = dw + (size_t)cur * 256 + lane * 4;
                atomicAdd(dwp + 0, acc.x); atomicAdd(dwp + 1, acc.y);
                atomicAdd(dwp + 2, acc.z); atomicAdd(dwp + 3, acc.w);
            }
            cur = c; acc = x4;
        } else {
            acc.x += x4.x; acc.y += x4.y; acc.z += x4.z; acc.w += x4.w;
        }
    }
    if (cur >= 0) {
        float* dwp = dw + (size_t)cur * 256 + lane * 4;
        atomicAdd(dwp + 0, acc.x); atomicAdd(dwp + 1, acc.y);
        atomicAdd(dwp + 2, acc.z); atomicAdd(dwp + 3, acc.w);
    }
}

// --------------------------------------------- streaming epilogue per token
__global__ __launch_bounds__(256) void epilogue_token(
    const float* __restrict__ X, const float* __restrict__ W,
    const int* __restrict__ idx, float* __restrict__ out,
    float* __restrict__ elat_arr)
{
    int gid = blockIdx.x * 256 + threadIdx.x;
    int t = gid >> 6, q = gid & 63;
    int code = idx[t];
    float4 x4 = ((const float4*)X)[gid];
    float4 w4 = ((const float4*)W)[(size_t)code * 64 + q];
    ((float4*)(out + O_Q))[gid] = w4;
    float dx0 = w4.x - x4.x, dx1 = w4.y - x4.y, dx2 = w4.z - x4.z, dx3 = w4.w - x4.w;
    float e = dx0 * dx0 + dx1 * dx1 + dx2 * dx2 + dx3 * dx3;
    if (q == 0) out[O_IDX + t] = (float)code;
#pragma unroll
    for (int off = 1; off < 64; off <<= 1) e += __shfl_xor(e, off);
    __shared__ float se[4];
    int lane = threadIdx.x & 63, wid = threadIdx.x >> 6;
    if (lane == 0) se[wid] = e;
    __syncthreads();
    if (threadIdx.x == 0) elat_arr[blockIdx.x] = se[0] + se[1] + se[2] + se[3];
}

// ------------------------------------------------ cluster EMA + loss + perplexity
__global__ __launch_bounds__(1024) void finalize_small(
    const float* __restrict__ ecs, const float* __restrict__ counts,
    const float* __restrict__ elat_arr, float* __restrict__ out)
{
    int k = threadIdx.x;
    float cnt = counts[k];
    float nc = ecs[k] * (1.0f - MU_C) + MU_C * cnt;
    float p = cnt * (1.0f / 65536.0f);
    float h = p * logf(p + 1e-10f);
    float el = 0.f;
#pragma unroll
    for (int i = 0; i < 16; ++i) el += elat_arr[k + i * 1024];
    float rn = nc, rh = h, re = el;
#pragma unroll
    for (int off = 1; off < 64; off <<= 1) {
        rn += __shfl_xor(rn, off);
        rh += __shfl_xor(rh, off);
        re += __shfl_xor(re, off);
    }
    __shared__ float sn[16], sh[16], sef[16];
    int wid = k >> 6, lane = k & 63;
    if (lane == 0) { sn[wid] = rn; sh[wid] = rh; sef[wid] = re; }
    __syncthreads();
    float n = 0.0f, H = 0.0f, E = 0.0f;
#pragma unroll
    for (int i = 0; i < 16; ++i) { n += sn[i]; H += sh[i]; E += sef[i]; }
    out[O_NC + k] = (nc + EPS_C) / (n + 1024.0f * EPS_C) * n;
    if (k == 0) {
        out[O_LOSS] = 0.25f * (E * (1.0f / 16777216.0f));
        out[O_PERP] = expf(-H);
    }
}

// ------------------------------------------------ new_ema_w / new_embedding
__global__ void finalize_embed(const float* __restrict__ ema_w,
                               const float* __restrict__ dw, float* __restrict__ out)
{
    int gid = blockIdx.x * blockDim.x + threadIdx.x;   // < 262144
    int k = gid >> 8;
    float ew = ema_w[gid] * (1.0f - MU_C) + MU_C * dw[gid];
    out[O_NEW + gid] = ew;
    out[O_EMB + gid] = ew / out[O_NC + k];
}

extern "C" void kernel_launch(void* const* d_in, const int* in_sizes, int n_in,
                              void* d_out, int out_size, void* d_ws, size_t ws_size,
                              hipStream_t stream) {
    const float* X     = (const float*)d_in[0];
    const float* W     = (const float*)d_in[1];
    const float* ema_w = (const float*)d_in[2];
    const float* ecs   = (const float*)d_in[3];
    float*    out    = (float*)d_out;
    unsigned* wsu    = (unsigned*)d_ws;
    float*    wsf    = (float*)d_ws;
    int*      idx    = (int*)d_ws + W_IDX;
    unsigned* cnt    = wsu + W_CNT;
    unsigned* cursor = wsu + W_CUR;
    unsigned* offs   = wsu + W_OFF;
    float*    cntf   = wsf + W_CNTF;
    unsigned* nflag  = wsu + W_NFLAG;
    int*      flags  = (int*)d_ws + W_FLAG;
    int*      order  = (int*)d_ws + W_ORDER;
    float*    dw     = wsf + W_DW;
    float*    wsq    = wsf + W_WSQ;
    _Float16* Wh     = (_Float16*)(wsu + W_WH);
    float*    xsqf   = wsf + W_XSQF;
    float*    elatA  = wsf + W_ELATA;

    hipMemsetAsync(wsu + W_CNT, 0, 4098 * sizeof(unsigned), stream);  // cnt..elat
    hipMemsetAsync(wsf + W_DW,  0, 262144 * sizeof(float),  stream);  // dw
    hipLaunchKernelGGL(convert_wsq,    dim3(256),   dim3(256),  0, stream, W, Wh, wsq);
    hipLaunchKernelGGL(argmin_mfma,    dim3(512),   dim3(256),  0, stream, X, Wh, wsq, idx, nflag, flags);
    hipLaunchKernelGGL(cleanup_xsq,    dim3(256),   dim3(256),  0, stream, X, nflag, flags, xsqf);
    hipLaunchKernelGGL(cleanup_gemm,   dim3(128),   dim3(256),  0, stream, X, W, wsq, nflag, flags, xsqf, idx);
    hipLaunchKernelGGL(k_hist,         dim3(256),   dim3(256),  0, stream, idx, cnt);
    hipLaunchKernelGGL(k_scan,         dim3(1),     dim3(1024), 0, stream, cnt, offs, cntf);
    hipLaunchKernelGGL(k_scatter,      dim3(256),   dim3(256),  0, stream, idx, offs, cursor, order);
    hipLaunchKernelGGL(k_dw,           dim3(1024),  dim3(256),  0, stream, X, order, idx, dw);
    hipLaunchKernelGGL(epilogue_token, dim3(16384), dim3(256),  0, stream, X, W, idx, out, elatA);
    hipLaunchKernelGGL(finalize_small, dim3(1),     dim3(1024), 0, stream, ecs, cntf, elatA, out);
    hipLaunchKernelGGL(finalize_embed, dim3(1024),  dim3(256),  0, stream, ema_w, dw, out);
}

// Round 5
// 256.425 us; speedup vs baseline: 6.3023x; 1.9806x over previous
//
#include <hip/hip_runtime.h>

typedef _Float16 half8 __attribute__((ext_vector_type(8)));
typedef _Float16 half4 __attribute__((ext_vector_type(4)));
typedef float f32x4 __attribute__((ext_vector_type(4)));

// Problem constants
#define N_TOK 65536
#define DIM   256
#define KCODE 1024
#define MU_C  0.01f
#define EPS_C 1e-5f

// d_out offsets (floats), reference return order
#define O_Q    0
#define O_LOSS 16777216
#define O_IDX  16777217
#define O_PERP 16842753
#define O_NC   16842754
#define O_NEW  16843778
#define O_EMB  17105922

// d_ws offsets (4-byte words)
#define W_IDX   0         // int[65536]
#define W_CNT   65536     // u32[1024]
#define W_CUR   66560     // u32[1024]
#define W_OFF   67584     // u32[1024]
#define W_CNTF  68608     // float[1024]
#define W_NFLAG 69632     // u32[1]
#define W_ELAT  69633     // float[1]  (unused now)
#define W_FLAG  69696     // int[65536]
#define W_ORDER 135232    // int[65536]
#define W_DW    200768    // float[262144]
#define W_WSQ   462912    // float[1024]
#define W_WH    463936    // _Float16[262144] = 131072 words
#define W_XSQF  595008    // float[65536]  xsq of flagged tokens (compacted)
#define W_ELATA 660544    // float[16384]  per-block e_latent partial sums
#define W_PACK  676928    // u64[65536] packed (score,code) per flagged pos
// total: 808000 words = 3.23 MB

__device__ __forceinline__ int imin(int a, int b) { return a < b ? a : b; }
__device__ __forceinline__ int imax(int a, int b) { return a > b ? a : b; }

// ---------------------------------------- W -> f16 convert + row sum-of-squares
__global__ void convert_wsq(const float* __restrict__ W, _Float16* __restrict__ Wh,
                            float* __restrict__ wsq) {
    int gid = blockIdx.x * 256 + threadIdx.x;   // 1024 rows * 64 lanes
    int row = gid >> 6, lane = gid & 63;
    float4 v = *(const float4*)(W + (size_t)row * 256 + lane * 4);
    half4 h;
    h[0] = (_Float16)v.x; h[1] = (_Float16)v.y; h[2] = (_Float16)v.z; h[3] = (_Float16)v.w;
    *(half4*)(Wh + (size_t)row * 256 + lane * 4) = h;
    float s = v.x * v.x + v.y * v.y + v.z * v.z + v.w * v.w;
#pragma unroll
    for (int off = 1; off < 64; off <<= 1) s += __shfl_xor(s, off);
    if (lane == 0) wsq[row] = s;
}

// ------------------------------------------------------------- argmin via MFMA
// Block = 128 tokens, 4 waves x 32 rows. A (f16, whole K=256) in registers.
// B chunks of 64 codes double-buffered in LDS (2 x 32KB), 2-phase pipeline.
// Packed top-2 tracking; tokens with truncated gap < 0.125 flagged for exact
// fp32 re-scoring (trunc quantum 0.0625 -> f16 gap >= 0.0625 = 6.9 sigma).
__global__ __launch_bounds__(256, 2) void argmin_mfma(
    const float* __restrict__ X, const _Float16* __restrict__ Wh,
    const float* __restrict__ wsq, int* __restrict__ idx_out,
    unsigned* __restrict__ nflag, int* __restrict__ flaglist)
{
    __shared__ _Float16 Bs[2][64 * 256];   // 2 x 32 KB

    const int tid  = threadIdx.x;
    const int lane = tid & 63;
    const int w    = tid >> 6;
    const int l15  = lane & 15;
    const int lk   = lane >> 4;
    const int t0   = blockIdx.x * 128;

    half8 a[2][8];
#pragma unroll
    for (int mf = 0; mf < 2; ++mf) {
        const float* xr = X + (size_t)(t0 + w * 32 + mf * 16 + l15) * 256 + lk * 8;
#pragma unroll
        for (int g = 0; g < 8; ++g) {
            float4 u0 = *(const float4*)(xr + g * 32);
            float4 u1 = *(const float4*)(xr + g * 32 + 4);
            half8 h;
            h[0] = (_Float16)u0.x; h[1] = (_Float16)u0.y;
            h[2] = (_Float16)u0.z; h[3] = (_Float16)u0.w;
            h[4] = (_Float16)u1.x; h[5] = (_Float16)u1.y;
            h[6] = (_Float16)u1.z; h[7] = (_Float16)u1.w;
            a[mf][g] = h;
        }
    }

    int u1a[8], u2a[8];
#pragma unroll
    for (int i = 0; i < 8; ++i) { u1a[i] = 0x7FFFFFFF; u2a[i] = 0x7FFFFFFF; }

#define STAGE(cc, bb)                                                          \
    _Pragma("unroll")                                                          \
    for (int i = 0; i < 8; ++i) {                                              \
        int loff = (w * 8 + i) * 1024;                                         \
        int off  = loff + lane * 16;                                           \
        int row  = off >> 9;                                                   \
        int slot = (off >> 4) & 31;                                            \
        const _Float16* src = Wh + (size_t)((cc) * 64 + row) * 256             \
                                 + ((slot ^ (row & 7)) << 3);                  \
        __builtin_amdgcn_global_load_lds(                                      \
            (const __attribute__((address_space(1))) void*)src,                \
            (__attribute__((address_space(3))) void*)((char*)Bs[bb] + loff),   \
            16, 0, 0);                                                         \
    }

    STAGE(0, 0);
    __syncthreads();

    for (int c = 0; c < 16; ++c) {
        const int cur = c & 1;
        if (c < 15) { STAGE(c + 1, cur ^ 1); }

        f32x4 acc[2][4];
#pragma unroll
        for (int mf = 0; mf < 2; ++mf)
#pragma unroll
            for (int nf = 0; nf < 4; ++nf) acc[mf][nf] = (f32x4)0.0f;

#pragma unroll
        for (int ks = 0; ks < 4; ++ks) {
#pragma unroll
            for (int kk = 0; kk < 2; ++kk) {
                half8 b4[4];
#pragma unroll
                for (int nf = 0; nf < 4; ++nf) {
                    int row  = nf * 16 + l15;
                    int slot = ks * 8 + kk * 4 + lk;
                    b4[nf] = *(const half8*)((const char*)Bs[cur]
                              + row * 512 + ((slot ^ (row & 7)) << 4));
                }
#pragma unroll
                for (int nf = 0; nf < 4; ++nf) {
                    acc[0][nf] = __builtin_amdgcn_mfma_f32_16x16x32_f16(
                        a[0][ks * 2 + kk], b4[nf], acc[0][nf], 0, 0, 0);
                    acc[1][nf] = __builtin_amdgcn_mfma_f32_16x16x32_f16(
                        a[1][ks * 2 + kk], b4[nf], acc[1][nf], 0, 0, 0);
                }
            }
        }
#pragma unroll
        for (int nf = 0; nf < 4; ++nf) {
            int   code = c * 64 + nf * 16 + l15;
            float tc   = fmaf(0.5f, wsq[code], 512.0f);
#pragma unroll
            for (int mf = 0; mf < 2; ++mf)
#pragma unroll
                for (int r = 0; r < 4; ++r) {
                    float sv = tc - acc[mf][nf][r];
                    int u = (__float_as_int(sv) & 0xFFFFFC00) | code;
                    int s8 = mf * 4 + r;
                    u2a[s8] = imin(u2a[s8], imax(u1a[s8], u));
                    u1a[s8] = imin(u1a[s8], u);
                }
        }
        __syncthreads();
    }
#undef STAGE

#pragma unroll
    for (int s8 = 0; s8 < 8; ++s8) {
#pragma unroll
        for (int off = 1; off < 16; off <<= 1) {
            int b1 = __shfl_xor(u1a[s8], off);
            int b2 = __shfl_xor(u2a[s8], off);
            int n2 = imin(imin(u2a[s8], b2), imax(u1a[s8], b1));
            u1a[s8] = imin(u1a[s8], b1);
            u2a[s8] = n2;
        }
    }
    if (l15 == 0) {
#pragma unroll
        for (int s8 = 0; s8 < 8; ++s8) {
            int mf = s8 >> 2, r = s8 & 3;
            int row = t0 + w * 32 + mf * 16 + lk * 4 + r;
            idx_out[row] = u1a[s8] & 1023;
            float s1 = __int_as_float(u1a[s8] & 0xFFFFFC00);
            float s2 = __int_as_float(u2a[s8] & 0xFFFFFC00);
            if (s2 - s1 < 0.125f) {
                unsigned p = atomicAdd(nflag, 1u);
                flaglist[p] = row;
            }
        }
    }
}

// ------------------------------------ xsq for flagged tokens (compacted array)
__global__ void cleanup_xsq(const float* __restrict__ X,
                            const unsigned* __restrict__ nflagp,
                            const int* __restrict__ flaglist,
                            float* __restrict__ xsqf) {
    int n = (int)nflagp[0];
    int wid  = (blockIdx.x * 256 + threadIdx.x) >> 6;   // 1024 waves
    int lane = threadIdx.x & 63;
    for (int i = wid; i < n; i += 1024) {
        const float* row = X + (size_t)flaglist[i] * 256;
        float4 v = *(const float4*)(row + lane * 4);
        float s = v.x * v.x + v.y * v.y + v.z * v.z + v.w * v.w;
#pragma unroll
        for (int off = 1; off < 64; off <<= 1) s += __shfl_xor(s, off);
        if (lane == 0) xsqf[i] = s;
    }
}

// ------------- exact fp32 re-scoring, split (token-tile x code-chunk) blocks
// grid = 512: low 3 bits = code chunk (128 codes), high bits stride token tiles.
// Per-token global min via packed u64 atomicMin: (score_bits<<32)|code gives
// strict < with lowest-index tie-break (scores are all > 0).
#define BM 128
#define BK 16

__global__ __launch_bounds__(256) void cleanup_gemm(
    const float* __restrict__ X, const float* __restrict__ W,
    const float* __restrict__ wsq, const unsigned* __restrict__ nflagp,
    const int* __restrict__ flaglist, const float* __restrict__ xsqf,
    unsigned long long* __restrict__ pack)
{
    __shared__ float xs [BK][BM];
    __shared__ float wps[BK][128];
    __shared__ float wsq_s[128];

    const int n = (int)nflagp[0];
    const int tid  = threadIdx.x;
    const int tx   = tid & 15;
    const int ty   = tid >> 4;
    const int trow = tid >> 1;
    const int khalf = (tid & 1) * 8;
    const int c0   = (blockIdx.x & 7) * 128;

    for (int tile = blockIdx.x >> 3; tile * BM < n; tile += 64) {
        const int t0 = tile * BM;
        const int gtok = flaglist[imin(t0 + trow, n - 1)];

        float xsq_r[8];
#pragma unroll
        for (int i = 0; i < 8; ++i) xsq_r[i] = xsqf[imin(t0 + ty * 8 + i, n - 1)];

        float minv[8]; int mini[8];
#pragma unroll
        for (int i = 0; i < 8; ++i) { minv[i] = 3.402823466e+38f; mini[i] = 0; }

        float acc[8][8];
#pragma unroll
        for (int i = 0; i < 8; ++i)
#pragma unroll
            for (int j = 0; j < 8; ++j) acc[i][j] = 0.0f;

        for (int ks = 0; ks < DIM / BK; ++ks) {
            const int kb = ks * BK;
            __syncthreads();
            {
                const float* xr = X + (size_t)gtok * DIM + kb + khalf;
                float4 v0 = *(const float4*)xr;
                float4 v1 = *(const float4*)(xr + 4);
                xs[khalf + 0][trow] = v0.x; xs[khalf + 1][trow] = v0.y;
                xs[khalf + 2][trow] = v0.z; xs[khalf + 3][trow] = v0.w;
                xs[khalf + 4][trow] = v1.x; xs[khalf + 5][trow] = v1.y;
                xs[khalf + 6][trow] = v1.z; xs[khalf + 7][trow] = v1.w;
                const float* wr = W + (size_t)(c0 + trow) * DIM + kb + khalf;
                float4 u0 = *(const float4*)wr;
                float4 u1 = *(const float4*)(wr + 4);
                wps[khalf + 0][trow] = u0.x; wps[khalf + 1][trow] = u0.y;
                wps[khalf + 2][trow] = u0.z; wps[khalf + 3][trow] = u0.w;
                wps[khalf + 4][trow] = u1.x; wps[khalf + 5][trow] = u1.y;
                wps[khalf + 6][trow] = u1.z; wps[khalf + 7][trow] = u1.w;
                if (ks == 0 && tid < 128) wsq_s[tid] = wsq[c0 + tid];
            }
            __syncthreads();
#pragma unroll
            for (int kl = 0; kl < BK; ++kl) {
                float4 a0 = *(const float4*)&xs [kl][ty * 8];
                float4 a1 = *(const float4*)&xs [kl][ty * 8 + 4];
                float4 b0 = *(const float4*)&wps[kl][tx * 8];
                float4 b1 = *(const float4*)&wps[kl][tx * 8 + 4];
                float a[8] = {a0.x, a0.y, a0.z, a0.w, a1.x, a1.y, a1.z, a1.w};
                float b[8] = {b0.x, b0.y, b0.z, b0.w, b1.x, b1.y, b1.z, b1.w};
#pragma unroll
                for (int i = 0; i < 8; ++i)
#pragma unroll
                    for (int j = 0; j < 8; ++j)
                        acc[i][j] = fmaf(a[i], b[j], acc[i][j]);
            }
        }
        // exact-rounding scores, strict < keeps lowest index within chunk
#pragma unroll
        for (int i = 0; i < 8; ++i) {
#pragma unroll
            for (int j = 0; j < 8; ++j) {
                float t1 = xsq_r[i] + wsq_s[tx * 8 + j];
                float s  = t1 - 2.0f * acc[i][j];
                int   c  = c0 + tx * 8 + j;
                if (s < minv[i]) { minv[i] = s; mini[i] = c; }
            }
        }
#pragma unroll
        for (int i = 0; i < 8; ++i) {
#pragma unroll
            for (int off = 1; off < 16; off <<= 1) {
                float ov = __shfl_xor(minv[i], off);
                int   oi = __shfl_xor(mini[i], off);
                if (ov < minv[i] || (ov == minv[i] && oi < mini[i])) {
                    minv[i] = ov; mini[i] = oi;
                }
            }
        }
        if (tx == 0) {
#pragma unroll
            for (int i = 0; i < 8; ++i) {
                int pos = t0 + ty * 8 + i;
                if (pos < n) {
                    unsigned long long pu =
                        ((unsigned long long)(unsigned)__float_as_int(minv[i]) << 32)
                        | (unsigned)mini[i];
                    atomicMin(&pack[pos], pu);
                }
            }
        }
        __syncthreads();
    }
}

// ------------------------------------------------ unpack cleanup results
__global__ void cleanup_write(const unsigned* __restrict__ nflagp,
                              const int* __restrict__ flaglist,
                              const unsigned long long* __restrict__ pack,
                              int* __restrict__ idx_out) {
    int n = (int)nflagp[0];
    for (int i = blockIdx.x * 256 + threadIdx.x; i < n; i += 65536)
        idx_out[flaglist[i]] = (int)(pack[i] & 0xFFFFFFFFull);
}

// ------------------------------------------- histogram / scan / scatter / dw
__global__ void k_hist(const int* __restrict__ idx, unsigned* __restrict__ cnt) {
    int t = blockIdx.x * 256 + threadIdx.x;
    atomicAdd(&cnt[idx[t]], 1u);
}

__global__ __launch_bounds__(1024) void k_scan(const unsigned* __restrict__ cnt,
                                               unsigned* __restrict__ offs,
                                               float* __restrict__ cntf) {
    __shared__ unsigned s[1024];
    int k = threadIdx.x;
    unsigned v = cnt[k];
    s[k] = v; cntf[k] = (float)v;
    __syncthreads();
    for (int d = 1; d < 1024; d <<= 1) {
        unsigned add = (k >= d) ? s[k - d] : 0u;
        __syncthreads();
        s[k] += add;
        __syncthreads();
    }
    offs[k] = s[k] - v;
}

__global__ void k_scatter(const int* __restrict__ idx, const unsigned* __restrict__ offs,
                          unsigned* __restrict__ cursor, int* __restrict__ order) {
    int t = blockIdx.x * 256 + threadIdx.x;
    int c = idx[t];
    unsigned p = atomicAdd(&cursor[c], 1u);
    order[offs[c] + p] = t;
}

// Skew-immune dw: each wave owns 16 contiguous sorted positions, register-
// accumulates runs, one float4-atomic flush per run boundary.
__global__ __launch_bounds__(256) void k_dw(const float* __restrict__ X,
                                            const int* __restrict__ order,
                                            const int* __restrict__ idx,
                                            float* __restrict__ dw)
{
    int gw   = (blockIdx.x * 256 + threadIdx.x) >> 6;   // 4096 waves
    int lane = threadIdx.x & 63;
    int p0 = gw * 16;
    float4 acc = make_float4(0.f, 0.f, 0.f, 0.f);
    int cur = -1;
#pragma unroll 4
    for (int i = 0; i < 16; ++i) {
        int t = order[p0 + i];
        int c = idx[t];
        float4 x4 = *(const float4*)(X + (size_t)t * 256 + lane * 4);
        if (c != cur) {
            if (cur >= 0) {
                float* dwp = dw + (size_t)cur * 256 + lane * 4;
                atomicAdd(dwp + 0, acc.x); atomicAdd(dwp + 1, acc.y);
                atomicAdd(dwp + 2, acc.z); atomicAdd(dwp + 3, acc.w);
            }
            cur = c; acc = x4;
        } else {
            acc.x += x4.x; acc.y += x4.y; acc.z += x4.z; acc.w += x4.w;
        }
    }
    if (cur >= 0) {
        float* dwp = dw + (size_t)cur * 256 + lane * 4;
        atomicAdd(dwp + 0, acc.x); atomicAdd(dwp + 1, acc.y);
        atomicAdd(dwp + 2, acc.z); atomicAdd(dwp + 3, acc.w);
    }
}

// --------------------------------------------- streaming epilogue per token
__global__ __launch_bounds__(256) void epilogue_token(
    const float* __restrict__ X, const float* __restrict__ W,
    const int* __restrict__ idx, float* __restrict__ out,
    float* __restrict__ elat_arr)
{
    int gid = blockIdx.x * 256 + threadIdx.x;
    int t = gid >> 6, q = gid & 63;
    int code = idx[t];
    float4 x4 = ((const float4*)X)[gid];
    float4 w4 = ((const float4*)W)[(size_t)code * 64 + q];
    ((float4*)(out + O_Q))[gid] = w4;
    float dx0 = w4.x - x4.x, dx1 = w4.y - x4.y, dx2 = w4.z - x4.z, dx3 = w4.w - x4.w;
    float e = dx0 * dx0 + dx1 * dx1 + dx2 * dx2 + dx3 * dx3;
    if (q == 0) out[O_IDX + t] = (float)code;
#pragma unroll
    for (int off = 1; off < 64; off <<= 1) e += __shfl_xor(e, off);
    __shared__ float se[4];
    int lane = threadIdx.x & 63, wid = threadIdx.x >> 6;
    if (lane == 0) se[wid] = e;
    __syncthreads();
    if (threadIdx.x == 0) elat_arr[blockIdx.x] = se[0] + se[1] + se[2] + se[3];
}

// ------------------------------------------------ cluster EMA + loss + perplexity
__global__ __launch_bounds__(1024) void finalize_small(
    const float* __restrict__ ecs, const float* __restrict__ counts,
    const float* __restrict__ elat_arr, float* __restrict__ out)
{
    int k = threadIdx.x;
    float cnt = counts[k];
    float nc = ecs[k] * (1.0f - MU_C) + MU_C * cnt;
    float p = cnt * (1.0f / 65536.0f);
    float h = p * logf(p + 1e-10f);
    float el = 0.f;
#pragma unroll
    for (int i = 0; i < 16; ++i) el += elat_arr[k + i * 1024];
    float rn = nc, rh = h, re = el;
#pragma unroll
    for (int off = 1; off < 64; off <<= 1) {
        rn += __shfl_xor(rn, off);
        rh += __shfl_xor(rh, off);
        re += __shfl_xor(re, off);
    }
    __shared__ float sn[16], sh[16], sef[16];
    int wid = k >> 6, lane = k & 63;
    if (lane == 0) { sn[wid] = rn; sh[wid] = rh; sef[wid] = re; }
    __syncthreads();
    float n = 0.0f, H = 0.0f, E = 0.0f;
#pragma unroll
    for (int i = 0; i < 16; ++i) { n += sn[i]; H += sh[i]; E += sef[i]; }
    out[O_NC + k] = (nc + EPS_C) / (n + 1024.0f * EPS_C) * n;
    if (k == 0) {
        out[O_LOSS] = 0.25f * (E * (1.0f / 16777216.0f));
        out[O_PERP] = expf(-H);
    }
}

// ------------------------------------------------ new_ema_w / new_embedding
__global__ void finalize_embed(const float* __restrict__ ema_w,
                               const float* __restrict__ dw, float* __restrict__ out)
{
    int gid = blockIdx.x * blockDim.x + threadIdx.x;   // < 262144
    int k = gid >> 8;
    float ew = ema_w[gid] * (1.0f - MU_C) + MU_C * dw[gid];
    out[O_NEW + gid] = ew;
    out[O_EMB + gid] = ew / out[O_NC + k];
}

extern "C" void kernel_launch(void* const* d_in, const int* in_sizes, int n_in,
                              void* d_out, int out_size, void* d_ws, size_t ws_size,
                              hipStream_t stream) {
    const float* X     = (const float*)d_in[0];
    const float* W     = (const float*)d_in[1];
    const float* ema_w = (const float*)d_in[2];
    const float* ecs   = (const float*)d_in[3];
    float*    out    = (float*)d_out;
    unsigned* wsu    = (unsigned*)d_ws;
    float*    wsf    = (float*)d_ws;
    int*      idx    = (int*)d_ws + W_IDX;
    unsigned* cnt    = wsu + W_CNT;
    unsigned* cursor = wsu + W_CUR;
    unsigned* offs   = wsu + W_OFF;
    float*    cntf   = wsf + W_CNTF;
    unsigned* nflag  = wsu + W_NFLAG;
    int*      flags  = (int*)d_ws + W_FLAG;
    int*      order  = (int*)d_ws + W_ORDER;
    float*    dw     = wsf + W_DW;
    float*    wsq    = wsf + W_WSQ;
    _Float16* Wh     = (_Float16*)(wsu + W_WH);
    float*    xsqf   = wsf + W_XSQF;
    float*    elatA  = wsf + W_ELATA;
    unsigned long long* pack = (unsigned long long*)(wsu + W_PACK);

    hipMemsetAsync(wsu + W_CNT, 0, 4098 * sizeof(unsigned), stream);   // cnt..elat
    hipMemsetAsync(wsf + W_DW,  0, 262144 * sizeof(float),  stream);   // dw
    hipMemsetAsync(pack, 0xFF, 65536 * sizeof(unsigned long long), stream);
    hipLaunchKernelGGL(convert_wsq,    dim3(256),   dim3(256),  0, stream, W, Wh, wsq);
    hipLaunchKernelGGL(argmin_mfma,    dim3(512),   dim3(256),  0, stream, X, Wh, wsq, idx, nflag, flags);
    hipLaunchKernelGGL(cleanup_xsq,    dim3(256),   dim3(256),  0, stream, X, nflag, flags, xsqf);
    hipLaunchKernelGGL(cleanup_gemm,   dim3(512),   dim3(256),  0, stream, X, W, wsq, nflag, flags, xsqf, pack);
    hipLaunchKernelGGL(cleanup_write,  dim3(256),   dim3(256),  0, stream, nflag, flags, pack, idx);
    hipLaunchKernelGGL(k_hist,         dim3(256),   dim3(256),  0, stream, idx, cnt);
    hipLaunchKernelGGL(k_scan,         dim3(1),     dim3(1024), 0, stream, cnt, offs, cntf);
    hipLaunchKernelGGL(k_scatter,      dim3(256),   dim3(256),  0, stream, idx, offs, cursor, order);
    hipLaunchKernelGGL(k_dw,           dim3(1024),  dim3(256),  0, stream, X, order, idx, dw);
    hipLaunchKernelGGL(epilogue_token, dim3(16384), dim3(256),  0, stream, X, W, idx, out, elatA);
    hipLaunchKernelGGL(finalize_small, dim3(1),     dim3(1024), 0, stream, ecs, cntf, elatA, out);
    hipLaunchKernelGGL(finalize_embed, dim3(1024),  dim3(256),  0, stream, ema_w, dw, out);
}

// Round 6
// 233.672 us; speedup vs baseline: 6.9160x; 1.0974x over previous
//
#include <hip/hip_runtime.h>

typedef _Float16 half8 __attribute__((ext_vector_type(8)));
typedef _Float16 half4 __attribute__((ext_vector_type(4)));
typedef float f32x4 __attribute__((ext_vector_type(4)));

// Problem constants
#define N_TOK 65536
#define DIM   256
#define KCODE 1024
#define MU_C  0.01f
#define EPS_C 1e-5f

// d_out offsets (floats), reference return order
#define O_Q    0
#define O_LOSS 16777216
#define O_IDX  16777217
#define O_PERP 16842753
#define O_NC   16842754
#define O_NEW  16843778
#define O_EMB  17105922

// d_ws offsets (4-byte words)
#define W_IDX   0         // int[65536]
#define W_CNT   65536     // u32[1024]
#define W_CUR   66560     // u32[1024]
#define W_OFF   67584     // u32[1024]
#define W_CNTF  68608     // float[1024]
#define W_NFLAG 69632     // u32[1]
#define W_ELAT  69633     // float[1]  (unused)
#define W_FLAG  69696     // int[65536]
#define W_ORDER 135232    // int[65536]
#define W_DW    200768    // float[262144]
#define W_WSQ   462912    // float[1024]
#define W_WH    463936    // _Float16[262144] = 131072 words
#define W_XSQF  595008    // float[65536]
#define W_ELATA 660544    // float[16384]
#define W_PACK  676928    // u64[65536]
// total: 808000 words = 3.23 MB

__device__ __forceinline__ int imin(int a, int b) { return a < b ? a : b; }
__device__ __forceinline__ int imax(int a, int b) { return a > b ? a : b; }

// ---------------------------------------- W -> f16 convert + row sum-of-squares
__global__ void convert_wsq(const float* __restrict__ W, _Float16* __restrict__ Wh,
                            float* __restrict__ wsq) {
    int gid = blockIdx.x * 256 + threadIdx.x;   // 1024 rows * 64 lanes
    int row = gid >> 6, lane = gid & 63;
    float4 v = *(const float4*)(W + (size_t)row * 256 + lane * 4);
    half4 h;
    h[0] = (_Float16)v.x; h[1] = (_Float16)v.y; h[2] = (_Float16)v.z; h[3] = (_Float16)v.w;
    *(half4*)(Wh + (size_t)row * 256 + lane * 4) = h;
    float s = v.x * v.x + v.y * v.y + v.z * v.z + v.w * v.w;
#pragma unroll
    for (int off = 1; off < 64; off <<= 1) s += __shfl_xor(s, off);
    if (lane == 0) wsq[row] = s;
}

// ------------------------------------------------------------- argmin via MFMA
// Block = 64 tokens, 4 waves x 16 rows. Grid 1024 -> 4 blocks/CU (32KB LDS).
// A (f16, K=256) in registers; B chunks of 32 codes double-buffered (2x16KB).
// Same swizzle/top-2/flag numerics as the passing R5 kernel.
__global__ __launch_bounds__(256, 4) void argmin_mfma(
    const float* __restrict__ X, const _Float16* __restrict__ Wh,
    const float* __restrict__ wsq, int* __restrict__ idx_out,
    unsigned* __restrict__ nflag, int* __restrict__ flaglist)
{
    __shared__ _Float16 Bs[2][32 * 256];   // 2 x 16 KB

    const int tid  = threadIdx.x;
    const int lane = tid & 63;
    const int w    = tid >> 6;          // wave 0..3 -> token rows w*16..
    const int l15  = lane & 15;
    const int lk   = lane >> 4;         // 0..3
    const int t0   = blockIdx.x * 64;

    // A fragments: row t0 + w*16 + l15, k = g*32 + lk*8 + e
    half8 a[8];
    {
        const float* xr = X + (size_t)(t0 + w * 16 + l15) * 256 + lk * 8;
#pragma unroll
        for (int g = 0; g < 8; ++g) {
            float4 u0 = *(const float4*)(xr + g * 32);
            float4 u1 = *(const float4*)(xr + g * 32 + 4);
            half8 h;
            h[0] = (_Float16)u0.x; h[1] = (_Float16)u0.y;
            h[2] = (_Float16)u0.z; h[3] = (_Float16)u0.w;
            h[4] = (_Float16)u1.x; h[5] = (_Float16)u1.y;
            h[6] = (_Float16)u1.z; h[7] = (_Float16)u1.w;
            a[g] = h;
        }
    }

    int u1a[4], u2a[4];
#pragma unroll
    for (int i = 0; i < 4; ++i) { u1a[i] = 0x7FFFFFFF; u2a[i] = 0x7FFFFFFF; }

#define STAGE(cc, bb)                                                          \
    _Pragma("unroll")                                                          \
    for (int i = 0; i < 4; ++i) {                                              \
        int loff = (w * 4 + i) * 1024;                                         \
        int off  = loff + lane * 16;                                           \
        int row  = off >> 9;                                                   \
        int slot = (off >> 4) & 31;                                            \
        const _Float16* src = Wh + (size_t)((cc) * 32 + row) * 256             \
                                 + ((slot ^ (row & 7)) << 3);                  \
        __builtin_amdgcn_global_load_lds(                                      \
            (const __attribute__((address_space(1))) void*)src,                \
            (__attribute__((address_space(3))) void*)((char*)Bs[bb] + loff),   \
            16, 0, 0);                                                         \
    }

    STAGE(0, 0);
    __syncthreads();

    for (int c = 0; c < 32; ++c) {        // 32 chunks of 32 codes
        const int cur = c & 1;
        if (c < 31) { STAGE(c + 1, cur ^ 1); }

        f32x4 acc[2];
        acc[0] = (f32x4)0.0f; acc[1] = (f32x4)0.0f;

        __builtin_amdgcn_s_setprio(1);
#pragma unroll
        for (int ks = 0; ks < 4; ++ks) {
#pragma unroll
            for (int kk = 0; kk < 2; ++kk) {
                int slot = ks * 8 + kk * 4 + lk;
                int sw   = (slot ^ (l15 & 7)) << 4;     // (16+l15)&7 == l15&7
                half8 b0 = *(const half8*)((const char*)Bs[cur] + l15 * 512 + sw);
                half8 b1 = *(const half8*)((const char*)Bs[cur] + (16 + l15) * 512 + sw);
                acc[0] = __builtin_amdgcn_mfma_f32_16x16x32_f16(
                    a[ks * 2 + kk], b0, acc[0], 0, 0, 0);
                acc[1] = __builtin_amdgcn_mfma_f32_16x16x32_f16(
                    a[ks * 2 + kk], b1, acc[1], 0, 0, 0);
            }
        }
        __builtin_amdgcn_s_setprio(0);

        // chunk epilogue: scores + packed top-2 update (token = lk*4 + r)
#pragma unroll
        for (int nf = 0; nf < 2; ++nf) {
            int   code = c * 32 + nf * 16 + l15;
            float tc   = fmaf(0.5f, wsq[code], 512.0f);
#pragma unroll
            for (int r = 0; r < 4; ++r) {
                float sv = tc - acc[nf][r];
                int u = (__float_as_int(sv) & 0xFFFFFC00) | code;
                u2a[r] = imin(u2a[r], imax(u1a[r], u));
                u1a[r] = imin(u1a[r], u);
            }
        }
        __syncthreads();
    }
#undef STAGE

    // reduce top-2 across the 16 l15 lanes sharing each token row
#pragma unroll
    for (int r = 0; r < 4; ++r) {
#pragma unroll
        for (int off = 1; off < 16; off <<= 1) {
            int b1 = __shfl_xor(u1a[r], off);
            int b2 = __shfl_xor(u2a[r], off);
            int n2 = imin(imin(u2a[r], b2), imax(u1a[r], b1));
            u1a[r] = imin(u1a[r], b1);
            u2a[r] = n2;
        }
    }
    if (l15 == 0) {
#pragma unroll
        for (int r = 0; r < 4; ++r) {
            int row = t0 + w * 16 + lk * 4 + r;
            idx_out[row] = u1a[r] & 1023;
            float s1 = __int_as_float(u1a[r] & 0xFFFFFC00);
            float s2 = __int_as_float(u2a[r] & 0xFFFFFC00);
            if (s2 - s1 < 0.125f) {
                unsigned p = atomicAdd(nflag, 1u);
                flaglist[p] = row;
            }
        }
    }
}

// ------------------------------------ xsq for flagged tokens (compacted array)
__global__ void cleanup_xsq(const float* __restrict__ X,
                            const unsigned* __restrict__ nflagp,
                            const int* __restrict__ flaglist,
                            float* __restrict__ xsqf) {
    int n = (int)nflagp[0];
    int wid  = (blockIdx.x * 256 + threadIdx.x) >> 6;   // 1024 waves
    int lane = threadIdx.x & 63;
    for (int i = wid; i < n; i += 1024) {
        const float* row = X + (size_t)flaglist[i] * 256;
        float4 v = *(const float4*)(row + lane * 4);
        float s = v.x * v.x + v.y * v.y + v.z * v.z + v.w * v.w;
#pragma unroll
        for (int off = 1; off < 64; off <<= 1) s += __shfl_xor(s, off);
        if (lane == 0) xsqf[i] = s;
    }
}

// ------------- exact fp32 re-scoring, 64-token x 128-code blocks, reg-prefetch
// grid 2048: low 3 bits = code chunk (128 codes), high bits = token tile slot.
// Per-token global min via packed u64 atomicMin ((score<<32)|code, scores > 0).
__global__ __launch_bounds__(256, 2) void cleanup_gemm(
    const float* __restrict__ X, const float* __restrict__ W,
    const float* __restrict__ wsq, const unsigned* __restrict__ nflagp,
    const int* __restrict__ flaglist, const float* __restrict__ xsqf,
    unsigned long long* __restrict__ pack)
{
    __shared__ float xs [16][64];
    __shared__ float wps[16][128];
    __shared__ float wsq_s[128];

    const int n = (int)nflagp[0];
    const int tid = threadIdx.x;
    const int tx  = tid & 15;            // 16 -> 8 codes each
    const int ty  = tid >> 4;            // 16 -> 4 rows each
    const int c0    = (blockIdx.x & 7) * 128;
    const int tslot = blockIdx.x >> 3;   // 0..255
    const int srow_x = tid & 63,  sq_x = tid >> 6;    // X stage: row, k-quarter
    const int srow_w = tid & 127, sh_w = tid >> 7;    // W stage: row, k-half

    if (tid < 128) wsq_s[tid] = wsq[c0 + tid];

    for (int tile = tslot; tile * 64 < n; tile += 256) {
        const int t0 = tile * 64;
        const int gtok = flaglist[imin(t0 + srow_x, n - 1)];
        const float* xrow = X + (size_t)gtok * DIM;
        const float* wrow = W + (size_t)(c0 + srow_w) * DIM + sh_w * 8;

        float xsq_r[4];
#pragma unroll
        for (int i = 0; i < 4; ++i) xsq_r[i] = xsqf[imin(t0 + ty * 4 + i, n - 1)];

        float minv[4]; int mini[4];
#pragma unroll
        for (int i = 0; i < 4; ++i) { minv[i] = 3.402823466e+38f; mini[i] = 0; }

        float acc[4][8];
#pragma unroll
        for (int i = 0; i < 4; ++i)
#pragma unroll
            for (int j = 0; j < 8; ++j) acc[i][j] = 0.0f;

        float4 xa = *(const float4*)(xrow + sq_x * 4);
        float4 wa = *(const float4*)(wrow);
        float4 wb = *(const float4*)(wrow + 4);

        for (int ks = 0; ks < 16; ++ks) {
            __syncthreads();             // previous readers done
            xs[sq_x * 4 + 0][srow_x] = xa.x; xs[sq_x * 4 + 1][srow_x] = xa.y;
            xs[sq_x * 4 + 2][srow_x] = xa.z; xs[sq_x * 4 + 3][srow_x] = xa.w;
            wps[sh_w * 8 + 0][srow_w] = wa.x; wps[sh_w * 8 + 1][srow_w] = wa.y;
            wps[sh_w * 8 + 2][srow_w] = wa.z; wps[sh_w * 8 + 3][srow_w] = wa.w;
            wps[sh_w * 8 + 4][srow_w] = wb.x; wps[sh_w * 8 + 5][srow_w] = wb.y;
            wps[sh_w * 8 + 6][srow_w] = wb.z; wps[sh_w * 8 + 7][srow_w] = wb.w;
            __syncthreads();
            if (ks < 15) {               // prefetch next K-slice (hides latency)
                xa = *(const float4*)(xrow + (ks + 1) * 16 + sq_x * 4);
                wa = *(const float4*)(wrow + (ks + 1) * 16);
                wb = *(const float4*)(wrow + (ks + 1) * 16 + 4);
            }
#pragma unroll
            for (int kl = 0; kl < 16; ++kl) {
                float4 av = *(const float4*)&xs [kl][ty * 4];
                float4 b0 = *(const float4*)&wps[kl][tx * 8];
                float4 b1 = *(const float4*)&wps[kl][tx * 8 + 4];
                float aa[4] = {av.x, av.y, av.z, av.w};
                float bb[8] = {b0.x, b0.y, b0.z, b0.w, b1.x, b1.y, b1.z, b1.w};
#pragma unroll
                for (int i = 0; i < 4; ++i)
#pragma unroll
                    for (int j = 0; j < 8; ++j)
                        acc[i][j] = fmaf(aa[i], bb[j], acc[i][j]);
            }
        }
        // exact-rounding scores, strict < keeps lowest index within chunk
#pragma unroll
        for (int i = 0; i < 4; ++i) {
#pragma unroll
            for (int j = 0; j < 8; ++j) {
                float t1 = xsq_r[i] + wsq_s[tx * 8 + j];
                float s  = t1 - 2.0f * acc[i][j];
                int   cc = c0 + tx * 8 + j;
                if (s < minv[i]) { minv[i] = s; mini[i] = cc; }
            }
        }
#pragma unroll
        for (int i = 0; i < 4; ++i) {
#pragma unroll
            for (int off = 1; off < 16; off <<= 1) {
                float ov = __shfl_xor(minv[i], off);
                int   oi = __shfl_xor(mini[i], off);
                if (ov < minv[i] || (ov == minv[i] && oi < mini[i])) {
                    minv[i] = ov; mini[i] = oi;
                }
            }
        }
        if (tx == 0) {
#pragma unroll
            for (int i = 0; i < 4; ++i) {
                int pos = t0 + ty * 4 + i;
                if (pos < n) {
                    unsigned long long pu =
                        ((unsigned long long)(unsigned)__float_as_int(minv[i]) << 32)
                        | (unsigned)mini[i];
                    atomicMin(&pack[pos], pu);
                }
            }
        }
        __syncthreads();
    }
}

// ------------------------------------------------ unpack cleanup results
__global__ void cleanup_write(const unsigned* __restrict__ nflagp,
                              const int* __restrict__ flaglist,
                              const unsigned long long* __restrict__ pack,
                              int* __restrict__ idx_out) {
    int n = (int)nflagp[0];
    for (int i = blockIdx.x * 256 + threadIdx.x; i < n; i += 65536)
        idx_out[flaglist[i]] = (int)(pack[i] & 0xFFFFFFFFull);
}

// ---------------------- streaming epilogue per token (+ histogram folded in)
__global__ __launch_bounds__(256) void epilogue_token(
    const float* __restrict__ X, const float* __restrict__ W,
    const int* __restrict__ idx, float* __restrict__ out,
    float* __restrict__ elat_arr, unsigned* __restrict__ cnt)
{
    int gid = blockIdx.x * 256 + threadIdx.x;
    int t = gid >> 6, q = gid & 63;
    int code = idx[t];
    float4 x4 = ((const float4*)X)[gid];
    float4 w4 = ((const float4*)W)[(size_t)code * 64 + q];
    ((float4*)(out + O_Q))[gid] = w4;
    float dx0 = w4.x - x4.x, dx1 = w4.y - x4.y, dx2 = w4.z - x4.z, dx3 = w4.w - x4.w;
    float e = dx0 * dx0 + dx1 * dx1 + dx2 * dx2 + dx3 * dx3;
    if (q == 0) {
        out[O_IDX + t] = (float)code;
        atomicAdd(&cnt[code], 1u);
    }
#pragma unroll
    for (int off = 1; off < 64; off <<= 1) e += __shfl_xor(e, off);
    __shared__ float se[4];
    int lane = threadIdx.x & 63, wid = threadIdx.x >> 6;
    if (lane == 0) se[wid] = e;
    __syncthreads();
    if (threadIdx.x == 0) elat_arr[blockIdx.x] = se[0] + se[1] + se[2] + se[3];
}

// ------------------------------------------------ scan via wave shuffles
__global__ __launch_bounds__(256) void k_scan(const unsigned* __restrict__ cnt,
                                              unsigned* __restrict__ offs,
                                              float* __restrict__ cntf) {
    int t = threadIdx.x, lane = t & 63, wid = t >> 6;
    uint4 v = ((const uint4*)cnt)[t];
    cntf[4 * t + 0] = (float)v.x; cntf[4 * t + 1] = (float)v.y;
    cntf[4 * t + 2] = (float)v.z; cntf[4 * t + 3] = (float)v.w;
    unsigned s = v.x + v.y + v.z + v.w;
    unsigned ps = s;
#pragma unroll
    for (int off = 1; off < 64; off <<= 1) {
        unsigned o = __shfl_up(ps, off);
        if (lane >= off) ps += o;
    }
    __shared__ unsigned wsum[4];
    if (lane == 63) wsum[wid] = ps;
    __syncthreads();
    unsigned base = 0;
#pragma unroll
    for (int i = 0; i < 4; ++i) if (i < wid) base += wsum[i];
    unsigned excl = base + ps - s;
    offs[4 * t + 0] = excl;
    offs[4 * t + 1] = excl + v.x;
    offs[4 * t + 2] = excl + v.x + v.y;
    offs[4 * t + 3] = excl + v.x + v.y + v.z;
}

__global__ void k_scatter(const int* __restrict__ idx, const unsigned* __restrict__ offs,
                          unsigned* __restrict__ cursor, int* __restrict__ order) {
    int t = blockIdx.x * 256 + threadIdx.x;
    int c = idx[t];
    unsigned p = atomicAdd(&cursor[c], 1u);
    order[offs[c] + p] = t;
}

// Skew-immune dw: each wave owns 16 contiguous sorted positions, register-
// accumulates runs, one float4-atomic flush per run boundary.
__global__ __launch_bounds__(256) void k_dw(const float* __restrict__ X,
                                            const int* __restrict__ order,
                                            const int* __restrict__ idx,
                                            float* __restrict__ dw)
{
    int gw   = (blockIdx.x * 256 + threadIdx.x) >> 6;   // 4096 waves
    int lane = threadIdx.x & 63;
    int p0 = gw * 16;
    float4 acc = make_float4(0.f, 0.f, 0.f, 0.f);
    int cur = -1;
#pragma unroll 4
    for (int i = 0; i < 16; ++i) {
        int t = order[p0 + i];
        int c = idx[t];
        float4 x4 = *(const float4*)(X + (size_t)t * 256 + lane * 4);
        if (c != cur) {
            if (cur >= 0) {
                float* dwp = dw + (size_t)cur * 256 + lane * 4;
                atomicAdd(dwp + 0, acc.x); atomicAdd(dwp + 1, acc.y);
                atomicAdd(dwp + 2, acc.z); atomicAdd(dwp + 3, acc.w);
            }
            cur = c; acc = x4;
        } else {
            acc.x += x4.x; acc.y += x4.y; acc.z += x4.z; acc.w += x4.w;
        }
    }
    if (cur >= 0) {
        float* dwp = dw + (size_t)cur * 256 + lane * 4;
        atomicAdd(dwp + 0, acc.x); atomicAdd(dwp + 1, acc.y);
        atomicAdd(dwp + 2, acc.z); atomicAdd(dwp + 3, acc.w);
    }
}

// ------------------------------------------------ cluster EMA + loss + perplexity
__global__ __launch_bounds__(1024) void finalize_small(
    const float* __restrict__ ecs, const float* __restrict__ counts,
    const float* __restrict__ elat_arr, float* __restrict__ out)
{
    int k = threadIdx.x;
    float cnt = counts[k];
    float nc = ecs[k] * (1.0f - MU_C) + MU_C * cnt;
    float p = cnt * (1.0f / 65536.0f);
    float h = p * logf(p + 1e-10f);
    float el = 0.f;
#pragma unroll
    for (int i = 0; i < 16; ++i) el += elat_arr[k + i * 1024];
    float rn = nc, rh = h, re = el;
#pragma unroll
    for (int off = 1; off < 64; off <<= 1) {
        rn += __shfl_xor(rn, off);
        rh += __shfl_xor(rh, off);
        re += __shfl_xor(re, off);
    }
    __shared__ float sn[16], sh[16], sef[16];
    int wid = k >> 6, lane = k & 63;
    if (lane == 0) { sn[wid] = rn; sh[wid] = rh; sef[wid] = re; }
    __syncthreads();
    float n = 0.0f, H = 0.0f, E = 0.0f;
#pragma unroll
    for (int i = 0; i < 16; ++i) { n += sn[i]; H += sh[i]; E += sef[i]; }
    out[O_NC + k] = (nc + EPS_C) / (n + 1024.0f * EPS_C) * n;
    if (k == 0) {
        out[O_LOSS] = 0.25f * (E * (1.0f / 16777216.0f));
        out[O_PERP] = expf(-H);
    }
}

// ------------------------------------------------ new_ema_w / new_embedding
__global__ void finalize_embed(const float* __restrict__ ema_w,
                               const float* __restrict__ dw, float* __restrict__ out)
{
    int gid = blockIdx.x * blockDim.x + threadIdx.x;   // < 262144
    int k = gid >> 8;
    float ew = ema_w[gid] * (1.0f - MU_C) + MU_C * dw[gid];
    out[O_NEW + gid] = ew;
    out[O_EMB + gid] = ew / out[O_NC + k];
}

extern "C" void kernel_launch(void* const* d_in, const int* in_sizes, int n_in,
                              void* d_out, int out_size, void* d_ws, size_t ws_size,
                              hipStream_t stream) {
    const float* X     = (const float*)d_in[0];
    const float* W     = (const float*)d_in[1];
    const float* ema_w = (const float*)d_in[2];
    const float* ecs   = (const float*)d_in[3];
    float*    out    = (float*)d_out;
    unsigned* wsu    = (unsigned*)d_ws;
    float*    wsf    = (float*)d_ws;
    int*      idx    = (int*)d_ws + W_IDX;
    unsigned* cnt    = wsu + W_CNT;
    unsigned* cursor = wsu + W_CUR;
    unsigned* offs   = wsu + W_OFF;
    float*    cntf   = wsf + W_CNTF;
    unsigned* nflag  = wsu + W_NFLAG;
    int*      flags  = (int*)d_ws + W_FLAG;
    int*      order  = (int*)d_ws + W_ORDER;
    float*    dw     = wsf + W_DW;
    float*    wsq    = wsf + W_WSQ;
    _Float16* Wh     = (_Float16*)(wsu + W_WH);
    float*    xsqf   = wsf + W_XSQF;
    float*    elatA  = wsf + W_ELATA;
    unsigned long long* pack = (unsigned long long*)(wsu + W_PACK);

    hipMemsetAsync(wsu + W_CNT, 0, 4098 * sizeof(unsigned), stream);   // cnt..elat
    hipMemsetAsync(wsf + W_DW,  0, 262144 * sizeof(float),  stream);   // dw
    hipMemsetAsync(pack, 0xFF, 65536 * sizeof(unsigned long long), stream);
    hipLaunchKernelGGL(convert_wsq,    dim3(256),   dim3(256),  0, stream, W, Wh, wsq);
    hipLaunchKernelGGL(argmin_mfma,    dim3(1024),  dim3(256),  0, stream, X, Wh, wsq, idx, nflag, flags);
    hipLaunchKernelGGL(cleanup_xsq,    dim3(256),   dim3(256),  0, stream, X, nflag, flags, xsqf);
    hipLaunchKernelGGL(cleanup_gemm,   dim3(2048),  dim3(256),  0, stream, X, W, wsq, nflag, flags, xsqf, pack);
    hipLaunchKernelGGL(cleanup_write,  dim3(256),   dim3(256),  0, stream, nflag, flags, pack, idx);
    hipLaunchKernelGGL(epilogue_token, dim3(16384), dim3(256),  0, stream, X, W, idx, out, elatA, cnt);
    hipLaunchKernelGGL(k_scan,         dim3(1),     dim3(256),  0, stream, cnt, offs, cntf);
    hipLaunchKernelGGL(k_scatter,      dim3(256),   dim3(256),  0, stream, idx, offs, cursor, order);
    hipLaunchKernelGGL(k_dw,           dim3(1024),  dim3(256),  0, stream, X, order, idx, dw);
    hipLaunchKernelGGL(finalize_small, dim3(1),     dim3(1024), 0, stream, ecs, cntf, elatA, out);
    hipLaunchKernelGGL(finalize_embed, dim3(1024),  dim3(256),  0, stream, ema_w, dw, out);
}